// Round 1
// baseline (567.228 us; speedup 1.0000x reference)
//
#include <hip/hip_runtime.h>
#include <stdint.h>

// Problem constants (B=2, S=2048, D=2048, H=16, HD=128)
#define S_LEN 2048
#define DMODEL 2048
#define NHEAD 16
#define HDIM 128

typedef __attribute__((ext_vector_type(8))) short short8;   // 8 bf16 (4 VGPRs)
typedef __attribute__((ext_vector_type(4))) float floatx4;  // MFMA acc

__device__ __forceinline__ unsigned short f2b(float f) {
  union { float f; unsigned u; } v; v.f = f;
  unsigned r = v.u + 0x7FFFu + ((v.u >> 16) & 1u);  // RNE
  return (unsigned short)(r >> 16);
}

// ---------------- fp32 -> bf16 conversion ----------------
__global__ __launch_bounds__(256) void cvt_bf16(const float* __restrict__ in,
                                                unsigned short* __restrict__ out, int n4) {
  int i = blockIdx.x * 256 + threadIdx.x;
  if (i >= n4) return;
  float4 f = ((const float4*)in)[i];
  ushort4 o;
  o.x = f2b(f.x); o.y = f2b(f.y); o.z = f2b(f.z); o.w = f2b(f.w);
  ((ushort4*)out)[i] = o;
}

// ---------------- GEMM: C = A @ Bw^T + bias, A:[M,K] bf16, Bw:[N,K] bf16 ----------------
// MODE 0: bf16 row-major out [M,N];  MODE 1: bf16 V-transposed out [(b*D+col)*S + s];
// MODE 2: fp32 row-major out.
template <int MODE>
__global__ __launch_bounds__(256)
void gemm_bt(const unsigned short* __restrict__ A, const unsigned short* __restrict__ Bw,
             const float* __restrict__ bias, void* __restrict__ Cout,
             int M, int N, int K, float scale) {
  constexpr int LD = 72;  // 64 + 8 pad: row pitch 144B -> 2-way LDS aliasing only (free)
  __shared__ unsigned short As[128 * LD];
  __shared__ unsigned short Bs[128 * LD];
  const int t = threadIdx.x;
  const int lane = t & 63, wave = t >> 6;
  const int quad = lane >> 4, lc = lane & 15;
  const int wm = wave >> 1, wn = wave & 1;  // 2x2 waves, 64x64 per wave
  const int m0 = blockIdx.y * 128, n0 = blockIdx.x * 128;
  const int srow = t >> 3, skc = (t & 7) * 8;  // staging: 32 rows x 8 chunks / pass

  floatx4 acc[4][4] = {};

  for (int kt = 0; kt < K; kt += 64) {
#pragma unroll
    for (int i = 0; i < 4; i++) {
      int row = i * 32 + srow;
      *(uint4*)&As[row * LD + skc] = *(const uint4*)&A[(size_t)(m0 + row) * K + kt + skc];
      *(uint4*)&Bs[row * LD + skc] = *(const uint4*)&Bw[(size_t)(n0 + row) * K + kt + skc];
    }
    __syncthreads();
#pragma unroll
    for (int ks = 0; ks < 2; ks++) {
      short8 av[4], bv[4];
#pragma unroll
      for (int mt = 0; mt < 4; mt++)
        av[mt] = *(const short8*)&As[(wm * 64 + mt * 16 + lc) * LD + ks * 32 + quad * 8];
#pragma unroll
      for (int nt = 0; nt < 4; nt++)
        bv[nt] = *(const short8*)&Bs[(wn * 64 + nt * 16 + lc) * LD + ks * 32 + quad * 8];
#pragma unroll
      for (int mt = 0; mt < 4; mt++)
#pragma unroll
        for (int nt = 0; nt < 4; nt++)
          acc[mt][nt] = __builtin_amdgcn_mfma_f32_16x16x32_bf16(av[mt], bv[nt], acc[mt][nt], 0, 0, 0);
    }
    __syncthreads();
  }

#pragma unroll
  for (int nt = 0; nt < 4; nt++) {
    const int col = n0 + wn * 64 + nt * 16 + lc;
    const float bcol = bias[col];
#pragma unroll
    for (int mt = 0; mt < 4; mt++) {
      const int row0 = m0 + wm * 64 + mt * 16 + quad * 4;
      if (MODE == 1) {
        // V^T layout: out[(b*D + col)*S + s], 4 consecutive s per lane -> one 8B store
        ushort4 o;
        o.x = f2b((acc[mt][nt][0] + bcol) * scale);
        o.y = f2b((acc[mt][nt][1] + bcol) * scale);
        o.z = f2b((acc[mt][nt][2] + bcol) * scale);
        o.w = f2b((acc[mt][nt][3] + bcol) * scale);
        int b = row0 >> 11;            // row0 / S_LEN
        int s = row0 & (S_LEN - 1);
        *(ushort4*)&((unsigned short*)Cout)[((size_t)(b * DMODEL + col)) * S_LEN + s] = o;
      } else {
#pragma unroll
        for (int r = 0; r < 4; r++) {
          float v = (acc[mt][nt][r] + bcol) * scale;
          if (MODE == 2)
            ((float*)Cout)[(size_t)(row0 + r) * N + col] = v;
          else
            ((unsigned short*)Cout)[(size_t)(row0 + r) * N + col] = f2b(v);
        }
      }
    }
  }
}

// ---------------- Flash attention (causal), bf16 in/out, fp32 softmax ----------------
// Q,K: [b,s,h,hd] rows of [B*S, D]; Vt: [b,h,hd,s]; O: [b,s,h,hd]. Q pre-scaled by 1/sqrt(HD).
__global__ __launch_bounds__(256)
void attn_fwd(const unsigned short* __restrict__ Qg, const unsigned short* __restrict__ Kg,
              const unsigned short* __restrict__ Vtg, unsigned short* __restrict__ Og) {
  constexpr int BM = 64, BN = 64;
  constexpr int LQ = 136;  // Q/K tile pitch (128+8)
  constexpr int LV = 72;   // Vt tile pitch (64+8)
  constexpr int LS = 66;   // score pitch (floats)
  constexpr int LP = 72;   // P tile pitch (64+8)
  __shared__ unsigned short Qs[BM * LQ];      // 17408 B
  __shared__ unsigned short KVs[HDIM * LV];   // 18432 B; K-tile view (BM*LQ=8704 elems) fits
  __shared__ float Ss[BM * LS];               // 16896 B
  __shared__ unsigned short Ps[BM * LP];      // 9216 B
  __shared__ float red1[BM * 4];
  __shared__ float red2[BM * 4];
  __shared__ float mrow[BM], lrow[BM], arow[BM];  // total ~64.8 KB -> 2 blocks/CU

  const int t = threadIdx.x;
  const int lane = t & 63, wave = t >> 6;
  const int quad = lane >> 4, lc = lane & 15;
  const int wm = wave >> 1, wn = wave & 1;
  const int qi = blockIdx.x, bh = blockIdx.y;
  const int b = bh >> 4, h = bh & 15;
  const int q0 = qi * BM;
  const size_t qkbase = (size_t)b * S_LEN * DMODEL + h * HDIM;
  const size_t vtbase = ((size_t)(b * DMODEL + h * HDIM)) * S_LEN;

  if (t < BM) { mrow[t] = -1e30f; lrow[t] = 0.f; }

  // stage Q tile once: 64 rows x 128 bf16
#pragma unroll
  for (int i = 0; i < 4; i++) {
    int idx = i * 256 + t, r = idx >> 4, c = (idx & 15) * 8;
    *(uint4*)&Qs[r * LQ + c] = *(const uint4*)&Qg[qkbase + (size_t)(q0 + r) * DMODEL + c];
  }

  floatx4 oacc[2][4] = {};  // O: rows wm*32+(0..31), cols wn*64+(0..63)
  __syncthreads();

  const int sr = t >> 2, sseg = t & 3;  // softmax: 4 threads per row
  const int qrow = q0 + sr;

  for (int kb = 0; kb <= qi; kb++) {
    const int k0 = kb * BN;
    // stage K tile (pitch LQ)
#pragma unroll
    for (int i = 0; i < 4; i++) {
      int idx = i * 256 + t, r = idx >> 4, c = (idx & 15) * 8;
      *(uint4*)&KVs[r * LQ + c] = *(const uint4*)&Kg[qkbase + (size_t)(k0 + r) * DMODEL + c];
    }
    __syncthreads();

    // S = Q @ K^T  (64x64; wave covers rows wm*32, cols wn*32; HD=128 -> 4 k-steps)
    floatx4 sacc[2][2] = {};
#pragma unroll
    for (int ks = 0; ks < 4; ks++) {
      short8 aq[2], bk[2];
#pragma unroll
      for (int mt = 0; mt < 2; mt++)
        aq[mt] = *(const short8*)&Qs[(wm * 32 + mt * 16 + lc) * LQ + ks * 32 + quad * 8];
#pragma unroll
      for (int nt = 0; nt < 2; nt++)
        bk[nt] = *(const short8*)&KVs[(wn * 32 + nt * 16 + lc) * LQ + ks * 32 + quad * 8];
#pragma unroll
      for (int mt = 0; mt < 2; mt++)
#pragma unroll
        for (int nt = 0; nt < 2; nt++)
          sacc[mt][nt] = __builtin_amdgcn_mfma_f32_16x16x32_bf16(aq[mt], bk[nt], sacc[mt][nt], 0, 0, 0);
    }
#pragma unroll
    for (int mt = 0; mt < 2; mt++)
#pragma unroll
      for (int nt = 0; nt < 2; nt++)
#pragma unroll
        for (int r = 0; r < 4; r++)
          Ss[(wm * 32 + mt * 16 + quad * 4 + r) * LS + wn * 32 + nt * 16 + lc] = sacc[mt][nt][r];
    __syncthreads();  // K-tile reads done; Ss visible

    // stage Vt tile into KVs (K view dead): 128 hd-rows x 64 s (pitch LV)
#pragma unroll
    for (int i = 0; i < 4; i++) {
      int idx = i * 256 + t, r = idx >> 3, c = (idx & 7) * 8;
      *(uint4*)&KVs[r * LV + c] = *(const uint4*)&Vtg[vtbase + (size_t)r * S_LEN + k0 + c];
    }

    // online softmax (fp32), causal mask applied here
    float mold = mrow[sr];
    float pmax = -1e30f;
#pragma unroll
    for (int c = 0; c < 16; c++) {
      int cc = sseg * 16 + c;
      float s = Ss[sr * LS + cc];
      if ((k0 + cc) <= qrow && s > pmax) pmax = s;
    }
    red1[sr * 4 + sseg] = pmax;
    __syncthreads();
    float mnew = fmaxf(fmaxf(red1[sr * 4], red1[sr * 4 + 1]),
                       fmaxf(red1[sr * 4 + 2], red1[sr * 4 + 3]));
    mnew = fmaxf(mold, mnew);
    float alpha = __expf(mold - mnew);
    float psum = 0.f;
#pragma unroll
    for (int c = 0; c < 16; c++) {
      int cc = sseg * 16 + c;
      float s = Ss[sr * LS + cc];
      float p = ((k0 + cc) <= qrow) ? __expf(s - mnew) : 0.f;
      psum += p;
      Ps[sr * LP + cc] = f2b(p);
    }
    red2[sr * 4 + sseg] = psum;
    if (sseg == 0) { mrow[sr] = mnew; arow[sr] = alpha; }
    __syncthreads();  // Ps/Vt/arow/red2 visible
    if (sseg == 0)
      lrow[sr] = lrow[sr] * alpha + red2[sr * 4] + red2[sr * 4 + 1] + red2[sr * 4 + 2] + red2[sr * 4 + 3];

    // rescale O accumulator by alpha(row)
#pragma unroll
    for (int mt = 0; mt < 2; mt++)
#pragma unroll
      for (int r = 0; r < 4; r++) {
        float a = arow[wm * 32 + mt * 16 + quad * 4 + r];
#pragma unroll
        for (int nt = 0; nt < 4; nt++) oacc[mt][nt][r] *= a;
      }

    // O += P @ V  (A=Ps [64 x 64], B from Vt [n=hd][k=s]; 2 k-steps)
#pragma unroll
    for (int ks = 0; ks < 2; ks++) {
      short8 ap[2], bv[4];
#pragma unroll
      for (int mt = 0; mt < 2; mt++)
        ap[mt] = *(const short8*)&Ps[(wm * 32 + mt * 16 + lc) * LP + ks * 32 + quad * 8];
#pragma unroll
      for (int nt = 0; nt < 4; nt++)
        bv[nt] = *(const short8*)&KVs[(wn * 64 + nt * 16 + lc) * LV + ks * 32 + quad * 8];
#pragma unroll
      for (int mt = 0; mt < 2; mt++)
#pragma unroll
        for (int nt = 0; nt < 4; nt++)
          oacc[mt][nt] = __builtin_amdgcn_mfma_f32_16x16x32_bf16(ap[mt], bv[nt], oacc[mt][nt], 0, 0, 0);
    }
    __syncthreads();  // protect KVs/Ps/Ss for next iteration
  }

  // epilogue: O /= l, write bf16 [b,s,h,hd]
#pragma unroll
  for (int mt = 0; mt < 2; mt++)
#pragma unroll
    for (int r = 0; r < 4; r++) {
      int row = wm * 32 + mt * 16 + quad * 4 + r;
      float inv = 1.f / lrow[row];
      size_t obase = ((size_t)(b * S_LEN + q0 + row)) * DMODEL + h * HDIM;
#pragma unroll
      for (int nt = 0; nt < 4; nt++)
        Og[obase + wn * 64 + nt * 16 + lc] = f2b(oacc[mt][nt][r] * inv);
    }
}

// ---------------- launch ----------------
extern "C" void kernel_launch(void* const* d_in, const int* in_sizes, int n_in,
                              void* d_out, int out_size, void* d_ws, size_t ws_size,
                              hipStream_t stream) {
  const float* x  = (const float*)d_in[0];
  const float* Wq = (const float*)d_in[1];
  const float* bq = (const float*)d_in[2];
  const float* Wk = (const float*)d_in[3];
  const float* bk = (const float*)d_in[4];
  const float* Wv = (const float*)d_in[5];
  const float* bv = (const float*)d_in[6];
  const float* Wo = (const float*)d_in[7];
  const float* bo = (const float*)d_in[8];

  const int M = 2 * S_LEN;  // 4096
  const int N = DMODEL, K = DMODEL;

  char* w = (char*)d_ws;  // needs 112 MB
  unsigned short* xb  = (unsigned short*)(w);
  unsigned short* Wqb = (unsigned short*)(w + (size_t)16 * (1 << 20));
  unsigned short* Wkb = (unsigned short*)(w + (size_t)24 * (1 << 20));
  unsigned short* Wvb = (unsigned short*)(w + (size_t)32 * (1 << 20));
  unsigned short* Wob = (unsigned short*)(w + (size_t)40 * (1 << 20));
  unsigned short* Qb  = (unsigned short*)(w + (size_t)48 * (1 << 20));
  unsigned short* Kb  = (unsigned short*)(w + (size_t)64 * (1 << 20));
  unsigned short* Vtb = (unsigned short*)(w + (size_t)80 * (1 << 20));
  unsigned short* Ob  = (unsigned short*)(w + (size_t)96 * (1 << 20));

  cvt_bf16<<<8192, 256, 0, stream>>>(x, xb, (M * K) / 4);
  cvt_bf16<<<4096, 256, 0, stream>>>(Wq, Wqb, (N * K) / 4);
  cvt_bf16<<<4096, 256, 0, stream>>>(Wk, Wkb, (N * K) / 4);
  cvt_bf16<<<4096, 256, 0, stream>>>(Wv, Wvb, (N * K) / 4);
  cvt_bf16<<<4096, 256, 0, stream>>>(Wo, Wob, (N * K) / 4);

  dim3 gg(N / 128, M / 128);
  const float qscale = 0.08838834764831843f;  // 1/sqrt(128), applied after bias like ref
  gemm_bt<0><<<gg, 256, 0, stream>>>(xb, Wqb, bq, Qb, M, N, K, qscale);
  gemm_bt<0><<<gg, 256, 0, stream>>>(xb, Wkb, bk, Kb, M, N, K, 1.f);
  gemm_bt<1><<<gg, 256, 0, stream>>>(xb, Wvb, bv, Vtb, M, N, K, 1.f);

  attn_fwd<<<dim3(S_LEN / 64, 2 * NHEAD), 256, 0, stream>>>(Qb, Kb, Vtb, Ob);

  gemm_bt<2><<<gg, 256, 0, stream>>>(Ob, Wob, bo, d_out, M, N, K, 1.f);
}

// Round 2
// 498.950 us; speedup vs baseline: 1.1368x; 1.1368x over previous
//
#include <hip/hip_runtime.h>
#include <stdint.h>

// Problem constants (B=2, S=2048, D=2048, H=16, HD=128)
#define S_LEN 2048
#define DMODEL 2048
#define NHEAD 16
#define HDIM 128

typedef __attribute__((ext_vector_type(8))) short short8;   // 8 bf16 (4 VGPRs)
typedef __attribute__((ext_vector_type(4))) float floatx4;  // MFMA acc

__device__ __forceinline__ unsigned short f2b(float f) {
  union { float f; unsigned u; } v; v.f = f;
  unsigned r = v.u + 0x7FFFu + ((v.u >> 16) & 1u);  // RNE
  return (unsigned short)(r >> 16);
}

// ---------------- fp32 -> bf16 conversion ----------------
__global__ __launch_bounds__(256) void cvt_bf16(const float* __restrict__ in,
                                                unsigned short* __restrict__ out, int n4) {
  int i = blockIdx.x * 256 + threadIdx.x;
  if (i >= n4) return;
  float4 f = ((const float4*)in)[i];
  ushort4 o;
  o.x = f2b(f.x); o.y = f2b(f.y); o.z = f2b(f.z); o.w = f2b(f.w);
  ((ushort4*)out)[i] = o;
}

// ---------------- GEMM: C = A @ Bw^T + bias, A:[M,K] bf16, Bw:[N,K] bf16 ----------------
// MODE 0: bf16 row-major out [M,N];  MODE 1: bf16 V-transposed out [(b*D+col)*S + s];
// MODE 2: fp32 row-major out.
template <int MODE>
__global__ __launch_bounds__(256)
void gemm_bt(const unsigned short* __restrict__ A, const unsigned short* __restrict__ Bw,
             const float* __restrict__ bias, void* __restrict__ Cout,
             int M, int N, int K, float scale) {
  constexpr int LD = 72;  // 64 + 8 pad: 144B row pitch -> 2-way LDS aliasing only (free)
  __shared__ unsigned short As[128 * LD];
  __shared__ unsigned short Bs[128 * LD];
  const int t = threadIdx.x;
  const int lane = t & 63, wave = t >> 6;
  const int quad = lane >> 4, lc = lane & 15;
  const int wm = wave >> 1, wn = wave & 1;  // 2x2 waves, 64x64 per wave
  const int m0 = blockIdx.y * 128, n0 = blockIdx.x * 128;
  const int srow = t >> 3, skc = (t & 7) * 8;  // staging: 32 rows x 8 chunks / pass

  floatx4 acc[4][4] = {};

  for (int kt = 0; kt < K; kt += 64) {
#pragma unroll
    for (int i = 0; i < 4; i++) {
      int row = i * 32 + srow;
      *(uint4*)&As[row * LD + skc] = *(const uint4*)&A[(size_t)(m0 + row) * K + kt + skc];
      *(uint4*)&Bs[row * LD + skc] = *(const uint4*)&Bw[(size_t)(n0 + row) * K + kt + skc];
    }
    __syncthreads();
#pragma unroll
    for (int ks = 0; ks < 2; ks++) {
      short8 av[4], bv[4];
#pragma unroll
      for (int mt = 0; mt < 4; mt++)
        av[mt] = *(const short8*)&As[(wm * 64 + mt * 16 + lc) * LD + ks * 32 + quad * 8];
#pragma unroll
      for (int nt = 0; nt < 4; nt++)
        bv[nt] = *(const short8*)&Bs[(wn * 64 + nt * 16 + lc) * LD + ks * 32 + quad * 8];
#pragma unroll
      for (int mt = 0; mt < 4; mt++)
#pragma unroll
        for (int nt = 0; nt < 4; nt++)
          acc[mt][nt] = __builtin_amdgcn_mfma_f32_16x16x32_bf16(av[mt], bv[nt], acc[mt][nt], 0, 0, 0);
    }
    __syncthreads();
  }

#pragma unroll
  for (int nt = 0; nt < 4; nt++) {
    const int col = n0 + wn * 64 + nt * 16 + lc;
    const float bcol = bias[col];
#pragma unroll
    for (int mt = 0; mt < 4; mt++) {
      const int row0 = m0 + wm * 64 + mt * 16 + quad * 4;
      if (MODE == 1) {
        // V^T layout: out[(b*D + col)*S + s], 4 consecutive s per lane -> one 8B store
        ushort4 o;
        o.x = f2b((acc[mt][nt][0] + bcol) * scale);
        o.y = f2b((acc[mt][nt][1] + bcol) * scale);
        o.z = f2b((acc[mt][nt][2] + bcol) * scale);
        o.w = f2b((acc[mt][nt][3] + bcol) * scale);
        int b = row0 >> 11;            // row0 / S_LEN
        int s = row0 & (S_LEN - 1);
        *(ushort4*)&((unsigned short*)Cout)[((size_t)(b * DMODEL + col)) * S_LEN + s] = o;
      } else {
#pragma unroll
        for (int r = 0; r < 4; r++) {
          float v = (acc[mt][nt][r] + bcol) * scale;
          if (MODE == 2)
            ((float*)Cout)[(size_t)(row0 + r) * N + col] = v;
          else
            ((unsigned short*)Cout)[(size_t)(row0 + r) * N + col] = f2b(v);
        }
      }
    }
  }
}

// ---------------- Flash attention (causal), bf16 in/out, in-register softmax ----------------
// Q,K: [b,s,h,hd] rows of [B*S, D]; Vt: [b,h,hd,s]; O: [b,s,h,hd]. Q pre-scaled by 1/sqrt(HD).
// Wave w owns S-rows [w*16, w*16+16) x all 64 cols. Softmax stats in registers via shfl_xor.
// Load balance: block bx processes q-tiles bx (bx+1 iters) and 31-bx (32-bx iters) = 33 total.
__global__ __launch_bounds__(256)
void attn_fwd(const unsigned short* __restrict__ Qg, const unsigned short* __restrict__ Kg,
              const unsigned short* __restrict__ Vtg, unsigned short* __restrict__ Og) {
  constexpr int LK = 136;  // K tile pitch (128+8) ushorts; 272B row -> 2-way aliasing
  constexpr int LV = 72;   // Vt tile pitch (64+8)
  constexpr int LP = 72;   // P tile pitch (64+8)
  __shared__ unsigned short Ks[64 * LK];     // 17408 B
  __shared__ unsigned short Vs[HDIM * LV];   // 18432 B
  __shared__ unsigned short Ps[64 * LP];     //  9216 B   -> 44 KB total

  const int t = threadIdx.x;
  const int lane = t & 63, w = t >> 6;
  const int quad = lane >> 4, lc = lane & 15;
  const int bh = blockIdx.y;
  const int b = bh >> 4, h = bh & 15;
  const size_t qkbase = (size_t)b * S_LEN * DMODEL + h * HDIM;
  const size_t vtbase = ((size_t)(b * DMODEL + h * HDIM)) * S_LEN;

  for (int rep = 0; rep < 2; rep++) {
    const int qi = rep ? (31 - (int)blockIdx.x) : (int)blockIdx.x;
    const int q0 = qi * 64;
    const int myrow = q0 + w * 16 + quad * 4;  // +r

    // Q A-frags straight into registers (each wave reads only its own 16 rows)
    short8 aq[4];
#pragma unroll
    for (int ks = 0; ks < 4; ks++)
      aq[ks] = *(const short8*)&Qg[qkbase + (size_t)(q0 + w * 16 + lc) * DMODEL + ks * 32 + quad * 8];

    floatx4 oacc[8] = {};  // rows w*16+quad*4+r, cols nt8*16+lc
    float m_run[4], l_run[4];
#pragma unroll
    for (int r = 0; r < 4; r++) { m_run[r] = -1e30f; l_run[r] = 0.f; }

    for (int kb = 0; kb <= qi; kb++) {
      const int k0 = kb * 64;
      __syncthreads();  // previous iter's LDS reads (Ks/Vs/Ps) complete
      // stage K tile: 64 rows x 128
#pragma unroll
      for (int i = 0; i < 4; i++) {
        int idx = i * 256 + t, r = idx >> 4, c = (idx & 15) * 8;
        *(uint4*)&Ks[r * LK + c] = *(const uint4*)&Kg[qkbase + (size_t)(k0 + r) * DMODEL + c];
      }
      // stage Vt tile: 128 hd-rows x 64 s
#pragma unroll
      for (int i = 0; i < 4; i++) {
        int idx = i * 256 + t, r = idx >> 3, c = (idx & 7) * 8;
        *(uint4*)&Vs[r * LV + c] = *(const uint4*)&Vtg[vtbase + (size_t)r * S_LEN + k0 + c];
      }
      __syncthreads();  // staging visible

      // S = Q @ K^T : wave's 16 rows x 64 cols
      floatx4 sacc[4] = {};
#pragma unroll
      for (int ks = 0; ks < 4; ks++) {
        short8 a = aq[ks];
#pragma unroll
        for (int nt = 0; nt < 4; nt++) {
          short8 bk = *(const short8*)&Ks[(nt * 16 + lc) * LK + ks * 32 + quad * 8];
          sacc[nt] = __builtin_amdgcn_mfma_f32_16x16x32_bf16(a, bk, sacc[nt], 0, 0, 0);
        }
      }

      // causal mask (only the diagonal tile needs it) + row max
      float mx[4] = {-1e30f, -1e30f, -1e30f, -1e30f};
      if (kb == qi) {
#pragma unroll
        for (int nt = 0; nt < 4; nt++) {
          int col = k0 + nt * 16 + lc;
#pragma unroll
          for (int r = 0; r < 4; r++) {
            if (col > myrow + r) sacc[nt][r] = -1e30f;
            mx[r] = fmaxf(mx[r], sacc[nt][r]);
          }
        }
      } else {
#pragma unroll
        for (int nt = 0; nt < 4; nt++)
#pragma unroll
          for (int r = 0; r < 4; r++) mx[r] = fmaxf(mx[r], sacc[nt][r]);
      }
#pragma unroll
      for (int off = 1; off < 16; off <<= 1)
#pragma unroll
        for (int r = 0; r < 4; r++) mx[r] = fmaxf(mx[r], __shfl_xor(mx[r], off));

      float alpha[4], rs[4];
#pragma unroll
      for (int r = 0; r < 4; r++) {
        float mnew = fmaxf(m_run[r], mx[r]);
        alpha[r] = __expf(m_run[r] - mnew);
        m_run[r] = mnew;
        rs[r] = 0.f;
      }
      // P = exp(S - m), write bf16 to LDS (own 16-row strip only)
#pragma unroll
      for (int nt = 0; nt < 4; nt++)
#pragma unroll
        for (int r = 0; r < 4; r++) {
          float p = __expf(sacc[nt][r] - m_run[r]);
          rs[r] += p;
          Ps[(w * 16 + quad * 4 + r) * LP + nt * 16 + lc] = f2b(p);
        }
#pragma unroll
      for (int off = 1; off < 16; off <<= 1)
#pragma unroll
        for (int r = 0; r < 4; r++) rs[r] += __shfl_xor(rs[r], off);
#pragma unroll
      for (int r = 0; r < 4; r++) l_run[r] = l_run[r] * alpha[r] + rs[r];

      // rescale O accumulator
#pragma unroll
      for (int nt8 = 0; nt8 < 8; nt8++)
#pragma unroll
        for (int r = 0; r < 4; r++) oacc[nt8][r] *= alpha[r];

      // O += P @ V  (wave reads its own Ps strip — same-wave LDS ordering, no barrier)
#pragma unroll
      for (int ks = 0; ks < 2; ks++) {
        short8 ap = *(const short8*)&Ps[(w * 16 + lc) * LP + ks * 32 + quad * 8];
#pragma unroll
        for (int nt8 = 0; nt8 < 8; nt8++) {
          short8 bv = *(const short8*)&Vs[(nt8 * 16 + lc) * LV + ks * 32 + quad * 8];
          oacc[nt8] = __builtin_amdgcn_mfma_f32_16x16x32_bf16(ap, bv, oacc[nt8], 0, 0, 0);
        }
      }
    }

    // epilogue: O /= l, write bf16 [b,s,h,hd]
#pragma unroll
    for (int r = 0; r < 4; r++) {
      float inv = 1.f / l_run[r];
      size_t obase = ((size_t)(b * S_LEN + myrow + r)) * DMODEL + h * HDIM;
#pragma unroll
      for (int nt8 = 0; nt8 < 8; nt8++)
        Og[obase + nt8 * 16 + lc] = f2b(oacc[nt8][r] * inv);
    }
  }
}

// ---------------- launch ----------------
extern "C" void kernel_launch(void* const* d_in, const int* in_sizes, int n_in,
                              void* d_out, int out_size, void* d_ws, size_t ws_size,
                              hipStream_t stream) {
  const float* x  = (const float*)d_in[0];
  const float* Wq = (const float*)d_in[1];
  const float* bq = (const float*)d_in[2];
  const float* Wk = (const float*)d_in[3];
  const float* bk = (const float*)d_in[4];
  const float* Wv = (const float*)d_in[5];
  const float* bv = (const float*)d_in[6];
  const float* Wo = (const float*)d_in[7];
  const float* bo = (const float*)d_in[8];

  const int M = 2 * S_LEN;  // 4096
  const int N = DMODEL, K = DMODEL;

  char* w = (char*)d_ws;  // needs 112 MB
  unsigned short* xb  = (unsigned short*)(w);
  unsigned short* Wqb = (unsigned short*)(w + (size_t)16 * (1 << 20));
  unsigned short* Wkb = (unsigned short*)(w + (size_t)24 * (1 << 20));
  unsigned short* Wvb = (unsigned short*)(w + (size_t)32 * (1 << 20));
  unsigned short* Wob = (unsigned short*)(w + (size_t)40 * (1 << 20));
  unsigned short* Qb  = (unsigned short*)(w + (size_t)48 * (1 << 20));
  unsigned short* Kb  = (unsigned short*)(w + (size_t)64 * (1 << 20));
  unsigned short* Vtb = (unsigned short*)(w + (size_t)80 * (1 << 20));
  unsigned short* Ob  = (unsigned short*)(w + (size_t)96 * (1 << 20));

  cvt_bf16<<<8192, 256, 0, stream>>>(x, xb, (M * K) / 4);
  cvt_bf16<<<4096, 256, 0, stream>>>(Wq, Wqb, (N * K) / 4);
  cvt_bf16<<<4096, 256, 0, stream>>>(Wk, Wkb, (N * K) / 4);
  cvt_bf16<<<4096, 256, 0, stream>>>(Wv, Wvb, (N * K) / 4);
  cvt_bf16<<<4096, 256, 0, stream>>>(Wo, Wob, (N * K) / 4);

  dim3 gg(N / 128, M / 128);
  const float qscale = 0.08838834764831843f;  // 1/sqrt(128), applied after bias like ref
  gemm_bt<0><<<gg, 256, 0, stream>>>(xb, Wqb, bq, Qb, M, N, K, qscale);
  gemm_bt<0><<<gg, 256, 0, stream>>>(xb, Wkb, bk, Kb, M, N, K, 1.f);
  gemm_bt<1><<<gg, 256, 0, stream>>>(xb, Wvb, bv, Vtb, M, N, K, 1.f);

  attn_fwd<<<dim3(16, 2 * NHEAD), 256, 0, stream>>>(Qb, Kb, Vtb, Ob);

  gemm_bt<2><<<gg, 256, 0, stream>>>(Ob, Wob, bo, d_out, M, N, K, 1.f);
}

// Round 3
// 464.262 us; speedup vs baseline: 1.2218x; 1.0747x over previous
//
#include <hip/hip_runtime.h>
#include <stdint.h>

// Problem constants (B=2, S=2048, D=2048, H=16, HD=128)
#define S_LEN 2048
#define DMODEL 2048
#define NHEAD 16
#define HDIM 128

typedef __attribute__((ext_vector_type(8))) short short8;   // 8 bf16 (4 VGPRs)
typedef __attribute__((ext_vector_type(4))) float floatx4;  // MFMA acc

__device__ __forceinline__ unsigned short f2b(float f) {
  union { float f; unsigned u; } v; v.f = f;
  unsigned r = v.u + 0x7FFFu + ((v.u >> 16) & 1u);  // RNE
  return (unsigned short)(r >> 16);
}

// async global->LDS, 16B per lane; LDS dest is wave-uniform base + lane*16
__device__ __forceinline__ void load_lds16(const unsigned short* g, unsigned short* l) {
  __builtin_amdgcn_global_load_lds((const __attribute__((address_space(1))) void*)g,
                                   (__attribute__((address_space(3))) void*)l, 16, 0, 0);
}

// ---------------- fused fp32 -> bf16 conversion (x in 2 slices + 4 weights) ----------------
__global__ __launch_bounds__(256) void cvt_all(const float* __restrict__ x,
                                               const float* __restrict__ Wq, const float* __restrict__ Wk,
                                               const float* __restrict__ Wv, const float* __restrict__ Wo,
                                               unsigned short* __restrict__ xb,
                                               unsigned short* __restrict__ Wqb, unsigned short* __restrict__ Wkb,
                                               unsigned short* __restrict__ Wvb, unsigned short* __restrict__ Wob) {
  const size_t idx = (size_t)blockIdx.x * 256 + threadIdx.x;  // < 2^20 per slice
  const int y = blockIdx.y;
  const float4* s; ushort4* d;
  if (y == 0)      { s = (const float4*)x;               d = (ushort4*)xb; }
  else if (y == 1) { s = (const float4*)x + (1u << 20);  d = (ushort4*)xb + (1u << 20); }
  else if (y == 2) { s = (const float4*)Wq;              d = (ushort4*)Wqb; }
  else if (y == 3) { s = (const float4*)Wk;              d = (ushort4*)Wkb; }
  else if (y == 4) { s = (const float4*)Wv;              d = (ushort4*)Wvb; }
  else             { s = (const float4*)Wo;              d = (ushort4*)Wob; }
  float4 f = s[idx];
  ushort4 o;
  o.x = f2b(f.x); o.y = f2b(f.y); o.z = f2b(f.z); o.w = f2b(f.w);
  d[idx] = o;
}

// ---------------- GEMM: C = A @ Bw^T + bias, A:[M,K] bf16, Bw:[N,K] bf16 ----------------
// m97-style: global_load_lds width=16 staging into unpadded [128][64] LDS tiles with
// XOR k-chunk swizzle (LDS[row][slot] = G[row][slot ^ (row&7)]) for bank spread.
// MODE 0: bf16 row-major out [M,N];  MODE 1: bf16 V-transposed out [(b*D+col)*S + s];
// MODE 2: fp32 row-major out.
template <int MODE>
__global__ __launch_bounds__(256)
void gemm_bt(const unsigned short* __restrict__ A, const unsigned short* __restrict__ Bw,
             const float* __restrict__ bias, void* __restrict__ Cout,
             int M, int N, int K, float scale) {
  __shared__ unsigned short As[128 * 64];  // 16 KB, NO padding (global_load_lds constraint)
  __shared__ unsigned short Bs[128 * 64];
  const int t = threadIdx.x;
  const int lane = t & 63, wave = t >> 6;
  const int quad = lane >> 4, lc = lane & 15;
  const int wm = wave >> 1, wn = wave & 1;  // 2x2 waves, 64x64 per wave
  const int m0 = blockIdx.y * 128, n0 = blockIdx.x * 128;

  // staging geometry: chunk c = wave*4+i covers rows c*8..c*8+8; lane covers
  // row c*8+(lane>>3), global k-chunk ((lane&7) ^ (lane>>3)) (XOR swizzle)
  const int srow = lane >> 3;
  const int skoff = ((lane & 7) ^ srow) * 8;
  const unsigned short* Ag[4];
  const unsigned short* Bg[4];
  unsigned short* Al[4];
  unsigned short* Bl[4];
#pragma unroll
  for (int i = 0; i < 4; i++) {
    int c = wave * 4 + i;
    Ag[i] = A + (size_t)(m0 + c * 8 + srow) * K + skoff;
    Bg[i] = Bw + (size_t)(n0 + c * 8 + srow) * K + skoff;
    Al[i] = &As[c * 512 + lane * 8];
    Bl[i] = &Bs[c * 512 + lane * 8];
  }

  // fragment-read swizzled k offsets (elements): want global chunk ks*4+quad at row r
  // -> LDS slot (ks*4+quad) ^ (r&7); our rows have r&7 == lc&7
  int koff[2];
#pragma unroll
  for (int ks = 0; ks < 2; ks++) koff[ks] = ((ks * 4 + quad) ^ (lc & 7)) * 8;

  floatx4 acc[4][4] = {};

  for (int kt = 0; kt < K; kt += 64) {
    if (kt) __syncthreads();  // protect LDS from overwrite while prior reads in flight
#pragma unroll
    for (int i = 0; i < 4; i++) {
      load_lds16(Ag[i] + kt, Al[i]);
      load_lds16(Bg[i] + kt, Bl[i]);
    }
    __syncthreads();  // drains vmcnt(0): staged tile visible
#pragma unroll
    for (int ks = 0; ks < 2; ks++) {
      short8 av[4], bv[4];
#pragma unroll
      for (int mt = 0; mt < 4; mt++)
        av[mt] = *(const short8*)&As[(wm * 64 + mt * 16 + lc) * 64 + koff[ks]];
#pragma unroll
      for (int nt = 0; nt < 4; nt++)
        bv[nt] = *(const short8*)&Bs[(wn * 64 + nt * 16 + lc) * 64 + koff[ks]];
#pragma unroll
      for (int mt = 0; mt < 4; mt++)
#pragma unroll
        for (int nt = 0; nt < 4; nt++)
          acc[mt][nt] = __builtin_amdgcn_mfma_f32_16x16x32_bf16(av[mt], bv[nt], acc[mt][nt], 0, 0, 0);
    }
  }

#pragma unroll
  for (int nt = 0; nt < 4; nt++) {
    const int col = n0 + wn * 64 + nt * 16 + lc;
    const float bcol = bias[col];
#pragma unroll
    for (int mt = 0; mt < 4; mt++) {
      const int row0 = m0 + wm * 64 + mt * 16 + quad * 4;
      if (MODE == 1) {
        // V^T layout: out[(b*D + col)*S + s], 4 consecutive s per lane -> one 8B store
        ushort4 o;
        o.x = f2b((acc[mt][nt][0] + bcol) * scale);
        o.y = f2b((acc[mt][nt][1] + bcol) * scale);
        o.z = f2b((acc[mt][nt][2] + bcol) * scale);
        o.w = f2b((acc[mt][nt][3] + bcol) * scale);
        int b = row0 >> 11;            // row0 / S_LEN
        int s = row0 & (S_LEN - 1);
        *(ushort4*)&((unsigned short*)Cout)[((size_t)(b * DMODEL + col)) * S_LEN + s] = o;
      } else {
#pragma unroll
        for (int r = 0; r < 4; r++) {
          float v = (acc[mt][nt][r] + bcol) * scale;
          if (MODE == 2)
            ((float*)Cout)[(size_t)(row0 + r) * N + col] = v;
          else
            ((unsigned short*)Cout)[(size_t)(row0 + r) * N + col] = f2b(v);
        }
      }
    }
  }
}

// ---------------- Flash attention (causal), bf16 in/out, in-register softmax ----------------
// Q,K: [b,s,h,hd] rows of [B*S, D]; Vt: [b,h,hd,s]; O: [b,s,h,hd]. Q pre-scaled by 1/sqrt(HD).
// Wave w owns S-rows [w*16, w*16+16) x all 64 cols. Softmax stats in registers via shfl_xor.
// Load balance: block bx processes q-tiles bx (bx+1 iters) and 31-bx (32-bx iters) = 33 total.
__global__ __launch_bounds__(256)
void attn_fwd(const unsigned short* __restrict__ Qg, const unsigned short* __restrict__ Kg,
              const unsigned short* __restrict__ Vtg, unsigned short* __restrict__ Og) {
  constexpr int LK = 136;  // K tile pitch (128+8) ushorts; 272B row -> 2-way aliasing
  constexpr int LV = 72;   // Vt tile pitch (64+8)
  constexpr int LP = 72;   // P tile pitch (64+8)
  __shared__ unsigned short Ks[64 * LK];     // 17408 B
  __shared__ unsigned short Vs[HDIM * LV];   // 18432 B
  __shared__ unsigned short Ps[64 * LP];     //  9216 B   -> 44 KB total

  const int t = threadIdx.x;
  const int lane = t & 63, w = t >> 6;
  const int quad = lane >> 4, lc = lane & 15;
  const int bh = blockIdx.y;
  const int b = bh >> 4, h = bh & 15;
  const size_t qkbase = (size_t)b * S_LEN * DMODEL + h * HDIM;
  const size_t vtbase = ((size_t)(b * DMODEL + h * HDIM)) * S_LEN;

  for (int rep = 0; rep < 2; rep++) {
    const int qi = rep ? (31 - (int)blockIdx.x) : (int)blockIdx.x;
    const int q0 = qi * 64;
    const int myrow = q0 + w * 16 + quad * 4;  // +r

    // Q A-frags straight into registers (each wave reads only its own 16 rows)
    short8 aq[4];
#pragma unroll
    for (int ks = 0; ks < 4; ks++)
      aq[ks] = *(const short8*)&Qg[qkbase + (size_t)(q0 + w * 16 + lc) * DMODEL + ks * 32 + quad * 8];

    floatx4 oacc[8] = {};  // rows w*16+quad*4+r, cols nt8*16+lc
    float m_run[4], l_run[4];
#pragma unroll
    for (int r = 0; r < 4; r++) { m_run[r] = -1e30f; l_run[r] = 0.f; }

    for (int kb = 0; kb <= qi; kb++) {
      const int k0 = kb * 64;
      __syncthreads();  // previous iter's LDS reads (Ks/Vs/Ps) complete
      // stage K tile: 64 rows x 128
#pragma unroll
      for (int i = 0; i < 4; i++) {
        int idx = i * 256 + t, r = idx >> 4, c = (idx & 15) * 8;
        *(uint4*)&Ks[r * LK + c] = *(const uint4*)&Kg[qkbase + (size_t)(k0 + r) * DMODEL + c];
      }
      // stage Vt tile: 128 hd-rows x 64 s
#pragma unroll
      for (int i = 0; i < 4; i++) {
        int idx = i * 256 + t, r = idx >> 3, c = (idx & 7) * 8;
        *(uint4*)&Vs[r * LV + c] = *(const uint4*)&Vtg[vtbase + (size_t)r * S_LEN + k0 + c];
      }
      __syncthreads();  // staging visible

      // S = Q @ K^T : wave's 16 rows x 64 cols
      floatx4 sacc[4] = {};
#pragma unroll
      for (int ks = 0; ks < 4; ks++) {
        short8 a = aq[ks];
#pragma unroll
        for (int nt = 0; nt < 4; nt++) {
          short8 bk = *(const short8*)&Ks[(nt * 16 + lc) * LK + ks * 32 + quad * 8];
          sacc[nt] = __builtin_amdgcn_mfma_f32_16x16x32_bf16(a, bk, sacc[nt], 0, 0, 0);
        }
      }

      // causal mask (only the diagonal tile needs it) + row max
      float mx[4] = {-1e30f, -1e30f, -1e30f, -1e30f};
      if (kb == qi) {
#pragma unroll
        for (int nt = 0; nt < 4; nt++) {
          int col = k0 + nt * 16 + lc;
#pragma unroll
          for (int r = 0; r < 4; r++) {
            if (col > myrow + r) sacc[nt][r] = -1e30f;
            mx[r] = fmaxf(mx[r], sacc[nt][r]);
          }
        }
      } else {
#pragma unroll
        for (int nt = 0; nt < 4; nt++)
#pragma unroll
          for (int r = 0; r < 4; r++) mx[r] = fmaxf(mx[r], sacc[nt][r]);
      }
#pragma unroll
      for (int off = 1; off < 16; off <<= 1)
#pragma unroll
        for (int r = 0; r < 4; r++) mx[r] = fmaxf(mx[r], __shfl_xor(mx[r], off));

      float alpha[4], rs[4];
#pragma unroll
      for (int r = 0; r < 4; r++) {
        float mnew = fmaxf(m_run[r], mx[r]);
        alpha[r] = __expf(m_run[r] - mnew);
        m_run[r] = mnew;
        rs[r] = 0.f;
      }
      // P = exp(S - m), write bf16 to LDS (own 16-row strip only)
#pragma unroll
      for (int nt = 0; nt < 4; nt++)
#pragma unroll
        for (int r = 0; r < 4; r++) {
          float p = __expf(sacc[nt][r] - m_run[r]);
          rs[r] += p;
          Ps[(w * 16 + quad * 4 + r) * LP + nt * 16 + lc] = f2b(p);
        }
#pragma unroll
      for (int off = 1; off < 16; off <<= 1)
#pragma unroll
        for (int r = 0; r < 4; r++) rs[r] += __shfl_xor(rs[r], off);
#pragma unroll
      for (int r = 0; r < 4; r++) l_run[r] = l_run[r] * alpha[r] + rs[r];

      // rescale O accumulator
#pragma unroll
      for (int nt8 = 0; nt8 < 8; nt8++)
#pragma unroll
        for (int r = 0; r < 4; r++) oacc[nt8][r] *= alpha[r];

      // O += P @ V  (wave reads its own Ps strip — same-wave LDS ordering, no barrier)
#pragma unroll
      for (int ks = 0; ks < 2; ks++) {
        short8 ap = *(const short8*)&Ps[(w * 16 + lc) * LP + ks * 32 + quad * 8];
#pragma unroll
        for (int nt8 = 0; nt8 < 8; nt8++) {
          short8 bv = *(const short8*)&Vs[(nt8 * 16 + lc) * LV + ks * 32 + quad * 8];
          oacc[nt8] = __builtin_amdgcn_mfma_f32_16x16x32_bf16(ap, bv, oacc[nt8], 0, 0, 0);
        }
      }
    }

    // epilogue: O /= l, write bf16 [b,s,h,hd]
#pragma unroll
    for (int r = 0; r < 4; r++) {
      float inv = 1.f / l_run[r];
      size_t obase = ((size_t)(b * S_LEN + myrow + r)) * DMODEL + h * HDIM;
#pragma unroll
      for (int nt8 = 0; nt8 < 8; nt8++)
        Og[obase + nt8 * 16 + lc] = f2b(oacc[nt8][r] * inv);
    }
  }
}

// ---------------- launch ----------------
extern "C" void kernel_launch(void* const* d_in, const int* in_sizes, int n_in,
                              void* d_out, int out_size, void* d_ws, size_t ws_size,
                              hipStream_t stream) {
  const float* x  = (const float*)d_in[0];
  const float* Wq = (const float*)d_in[1];
  const float* bq = (const float*)d_in[2];
  const float* Wk = (const float*)d_in[3];
  const float* bk = (const float*)d_in[4];
  const float* Wv = (const float*)d_in[5];
  const float* bv = (const float*)d_in[6];
  const float* Wo = (const float*)d_in[7];
  const float* bo = (const float*)d_in[8];

  const int M = 2 * S_LEN;  // 4096
  const int N = DMODEL, K = DMODEL;

  char* w = (char*)d_ws;  // needs 112 MB
  unsigned short* xb  = (unsigned short*)(w);
  unsigned short* Wqb = (unsigned short*)(w + (size_t)16 * (1 << 20));
  unsigned short* Wkb = (unsigned short*)(w + (size_t)24 * (1 << 20));
  unsigned short* Wvb = (unsigned short*)(w + (size_t)32 * (1 << 20));
  unsigned short* Wob = (unsigned short*)(w + (size_t)40 * (1 << 20));
  unsigned short* Qb  = (unsigned short*)(w + (size_t)48 * (1 << 20));
  unsigned short* Kb  = (unsigned short*)(w + (size_t)64 * (1 << 20));
  unsigned short* Vtb = (unsigned short*)(w + (size_t)80 * (1 << 20));
  unsigned short* Ob  = (unsigned short*)(w + (size_t)96 * (1 << 20));

  cvt_all<<<dim3(4096, 6), 256, 0, stream>>>(x, Wq, Wk, Wv, Wo, xb, Wqb, Wkb, Wvb, Wob);

  dim3 gg(N / 128, M / 128);
  const float qscale = 0.08838834764831843f;  // 1/sqrt(128), applied after bias like ref
  gemm_bt<0><<<gg, 256, 0, stream>>>(xb, Wqb, bq, Qb, M, N, K, qscale);
  gemm_bt<0><<<gg, 256, 0, stream>>>(xb, Wkb, bk, Kb, M, N, K, 1.f);
  gemm_bt<1><<<gg, 256, 0, stream>>>(xb, Wvb, bv, Vtb, M, N, K, 1.f);

  attn_fwd<<<dim3(16, 2 * NHEAD), 256, 0, stream>>>(Qb, Kb, Vtb, Ob);

  gemm_bt<2><<<gg, 256, 0, stream>>>(Ob, Wob, bo, d_out, M, N, K, 1.f);
}

// Round 4
// 411.256 us; speedup vs baseline: 1.3793x; 1.1289x over previous
//
#include <hip/hip_runtime.h>
#include <stdint.h>

// Problem constants (B=2, S=2048, D=2048, H=16, HD=128)
#define S_LEN 2048
#define DMODEL 2048
#define NHEAD 16
#define HDIM 128

typedef __attribute__((ext_vector_type(8))) short short8;   // 8 bf16 (4 VGPRs)
typedef __attribute__((ext_vector_type(4))) float floatx4;  // MFMA acc

__device__ __forceinline__ unsigned short f2b(float f) {
  union { float f; unsigned u; } v; v.f = f;
  unsigned r = v.u + 0x7FFFu + ((v.u >> 16) & 1u);  // RNE
  return (unsigned short)(r >> 16);
}

// async global->LDS, 16B per lane; LDS dest is wave-uniform base + lane*16
__device__ __forceinline__ void load_lds16(const unsigned short* g, unsigned short* l) {
  __builtin_amdgcn_global_load_lds((const __attribute__((address_space(1))) void*)g,
                                   (__attribute__((address_space(3))) void*)l, 16, 0, 0);
}

// ---------------- fused fp32 -> bf16 conversion (x in 2 slices + 4 weights) ----------------
__global__ __launch_bounds__(256) void cvt_all(const float* __restrict__ x,
                                               const float* __restrict__ Wq, const float* __restrict__ Wk,
                                               const float* __restrict__ Wv, const float* __restrict__ Wo,
                                               unsigned short* __restrict__ xb,
                                               unsigned short* __restrict__ Wqb, unsigned short* __restrict__ Wkb,
                                               unsigned short* __restrict__ Wvb, unsigned short* __restrict__ Wob) {
  const size_t idx = (size_t)blockIdx.x * 256 + threadIdx.x;  // < 2^20 per slice
  const int y = blockIdx.y;
  const float4* s; ushort4* d;
  if (y == 0)      { s = (const float4*)x;               d = (ushort4*)xb; }
  else if (y == 1) { s = (const float4*)x + (1u << 20);  d = (ushort4*)xb + (1u << 20); }
  else if (y == 2) { s = (const float4*)Wq;              d = (ushort4*)Wqb; }
  else if (y == 3) { s = (const float4*)Wk;              d = (ushort4*)Wkb; }
  else if (y == 4) { s = (const float4*)Wv;              d = (ushort4*)Wvb; }
  else             { s = (const float4*)Wo;              d = (ushort4*)Wob; }
  float4 f = s[idx];
  ushort4 o;
  o.x = f2b(f.x); o.y = f2b(f.y); o.z = f2b(f.z); o.w = f2b(f.w);
  d[idx] = o;
}

// ---------------- GEMM: C = A @ Bw^T + bias, A:[M,K] bf16, Bw:[N,K] bf16 ----------------
// m97-style: global_load_lds width=16 staging into unpadded [128][64] LDS tiles with
// XOR k-chunk swizzle (LDS[row][slot] = G[row][slot ^ (row&7)]) for bank spread.
// MODE 0: bf16 row-major out [M,N];  MODE 1: bf16 V-transposed out [(b*D+col)*S + s];
// MODE 2: fp32 row-major out.
template <int MODE>
__global__ __launch_bounds__(256)
void gemm_bt(const unsigned short* __restrict__ A, const unsigned short* __restrict__ Bw,
             const float* __restrict__ bias, void* __restrict__ Cout,
             int M, int N, int K, float scale) {
  __shared__ unsigned short As[128 * 64];  // 16 KB, NO padding (global_load_lds constraint)
  __shared__ unsigned short Bs[128 * 64];
  const int t = threadIdx.x;
  const int lane = t & 63, wave = t >> 6;
  const int quad = lane >> 4, lc = lane & 15;
  const int wm = wave >> 1, wn = wave & 1;  // 2x2 waves, 64x64 per wave
  const int m0 = blockIdx.y * 128, n0 = blockIdx.x * 128;

  // staging geometry: chunk c = wave*4+i covers rows c*8..c*8+8; lane covers
  // row c*8+(lane>>3), global k-chunk ((lane&7) ^ (lane>>3)) (XOR swizzle)
  const int srow = lane >> 3;
  const int skoff = ((lane & 7) ^ srow) * 8;
  const unsigned short* Ag[4];
  const unsigned short* Bg[4];
  unsigned short* Al[4];
  unsigned short* Bl[4];
#pragma unroll
  for (int i = 0; i < 4; i++) {
    int c = wave * 4 + i;
    Ag[i] = A + (size_t)(m0 + c * 8 + srow) * K + skoff;
    Bg[i] = Bw + (size_t)(n0 + c * 8 + srow) * K + skoff;
    Al[i] = &As[c * 512 + lane * 8];
    Bl[i] = &Bs[c * 512 + lane * 8];
  }

  // fragment-read swizzled k offsets (elements): want global chunk ks*4+quad at row r
  // -> LDS slot (ks*4+quad) ^ (r&7); our rows have r&7 == lc&7
  int koff[2];
#pragma unroll
  for (int ks = 0; ks < 2; ks++) koff[ks] = ((ks * 4 + quad) ^ (lc & 7)) * 8;

  floatx4 acc[4][4] = {};

  for (int kt = 0; kt < K; kt += 64) {
    if (kt) __syncthreads();  // protect LDS from overwrite while prior reads in flight
#pragma unroll
    for (int i = 0; i < 4; i++) {
      load_lds16(Ag[i] + kt, Al[i]);
      load_lds16(Bg[i] + kt, Bl[i]);
    }
    __syncthreads();  // drains vmcnt(0): staged tile visible
#pragma unroll
    for (int ks = 0; ks < 2; ks++) {
      short8 av[4], bv[4];
#pragma unroll
      for (int mt = 0; mt < 4; mt++)
        av[mt] = *(const short8*)&As[(wm * 64 + mt * 16 + lc) * 64 + koff[ks]];
#pragma unroll
      for (int nt = 0; nt < 4; nt++)
        bv[nt] = *(const short8*)&Bs[(wn * 64 + nt * 16 + lc) * 64 + koff[ks]];
#pragma unroll
      for (int mt = 0; mt < 4; mt++)
#pragma unroll
        for (int nt = 0; nt < 4; nt++)
          acc[mt][nt] = __builtin_amdgcn_mfma_f32_16x16x32_bf16(av[mt], bv[nt], acc[mt][nt], 0, 0, 0);
    }
  }

#pragma unroll
  for (int nt = 0; nt < 4; nt++) {
    const int col = n0 + wn * 64 + nt * 16 + lc;
    const float bcol = bias[col];
#pragma unroll
    for (int mt = 0; mt < 4; mt++) {
      const int row0 = m0 + wm * 64 + mt * 16 + quad * 4;
      if (MODE == 1) {
        // V^T layout: out[(b*D + col)*S + s], 4 consecutive s per lane -> one 8B store
        ushort4 o;
        o.x = f2b((acc[mt][nt][0] + bcol) * scale);
        o.y = f2b((acc[mt][nt][1] + bcol) * scale);
        o.z = f2b((acc[mt][nt][2] + bcol) * scale);
        o.w = f2b((acc[mt][nt][3] + bcol) * scale);
        int b = row0 >> 11;            // row0 / S_LEN
        int s = row0 & (S_LEN - 1);
        *(ushort4*)&((unsigned short*)Cout)[((size_t)(b * DMODEL + col)) * S_LEN + s] = o;
      } else {
#pragma unroll
        for (int r = 0; r < 4; r++) {
          float v = (acc[mt][nt][r] + bcol) * scale;
          if (MODE == 2)
            ((float*)Cout)[(size_t)(row0 + r) * N + col] = v;
          else
            ((unsigned short*)Cout)[(size_t)(row0 + r) * N + col] = f2b(v);
        }
      }
    }
  }
}

// ---------------- Flash attention (causal), BM=128, wave owns 32 q-rows ----------------
// Q,K: [b,s,h,hd] rows of [B*S, D]; Vt: [b,h,hd,s]; O: [b,s,h,hd]. Q pre-scaled by 1/sqrt(HD).
// K/V^T staged via global_load_lds into unpadded XOR-swizzled LDS; P same layout.
// Softmax fully in-register; row-sum kept lane-partial, reduced once in epilogue.
// Causal balance: grid(16,32); tile = (y<16)? x : 15-x pairs t with 15-t per CU.
__global__ __launch_bounds__(256, 2)
void attn_fwd(const unsigned short* __restrict__ Qg, const unsigned short* __restrict__ Kg,
              const unsigned short* __restrict__ Vtg, unsigned short* __restrict__ Og) {
  __shared__ unsigned short Ks[64 * 128];   // 16 KB [krow][chunk^(krow&15)]
  __shared__ unsigned short Vs[128 * 64];   // 16 KB [hd][chunk^(hd&7)]
  __shared__ unsigned short Ps[128 * 64];   // 16 KB [qrow][chunk^(qrow&7)]

  const int t = threadIdx.x;
  const int lane = t & 63, w = t >> 6;
  const int quad = lane >> 4, lc = lane & 15;
  const int y = blockIdx.y;
  const int tile = (y < 16) ? (int)blockIdx.x : 15 - (int)blockIdx.x;
  const int b = y >> 4, h = y & 15;
  const size_t qkbase = (size_t)b * S_LEN * DMODEL + h * HDIM;
  const size_t vtbase = ((size_t)(b * DMODEL + h * HDIM)) * S_LEN;
  const int q0 = tile * 128;
  const int wrow = q0 + w * 32;  // wave's first q-row

  // Q A-frags in registers: rows wrow + pm*16 + lc, k = ks*32 + quad*8
  short8 aq[2][4];
#pragma unroll
  for (int pm = 0; pm < 2; pm++)
#pragma unroll
    for (int ks = 0; ks < 4; ks++)
      aq[pm][ks] = *(const short8*)&Qg[qkbase + (size_t)(wrow + pm * 16 + lc) * DMODEL + ks * 32 + quad * 8];

  // staging pointers (chunk c = w*4+i)
  const unsigned short* kga[4];
  const unsigned short* vga[4];
  unsigned short* klds[4];
  unsigned short* vlds[4];
#pragma unroll
  for (int i = 0; i < 4; i++) {
    int c = w * 4 + i;
    int krow = 4 * c + (lane >> 4);
    int kch = (lane & 15) ^ (krow & 15);
    kga[i] = Kg + qkbase + (size_t)krow * DMODEL + kch * 8;
    klds[i] = &Ks[c * 512 + lane * 8];
    int vrow = 8 * c + (lane >> 3);
    int vch = (lane & 7) ^ (vrow & 7);
    vga[i] = Vtg + vtbase + (size_t)vrow * S_LEN + vch * 8;
    vlds[i] = &Vs[c * 512 + lane * 8];
  }

  floatx4 oacc[2][8] = {};
  float m_run[2][4], l_run[2][4];
#pragma unroll
  for (int pm = 0; pm < 2; pm++)
#pragma unroll
    for (int r = 0; r < 4; r++) { m_run[pm][r] = -1e30f; l_run[pm][r] = 0.f; }

  const int kiters = 2 * tile + 2;
  for (int kb = 0; kb < kiters; kb++) {
    const int k0 = kb * 64;
    if (kb) __syncthreads();  // prior iter's LDS reads complete before overwrite
#pragma unroll
    for (int i = 0; i < 4; i++) {
      load_lds16(kga[i] + (size_t)k0 * DMODEL, klds[i]);
      load_lds16(vga[i] + k0, vlds[i]);
    }
    __syncthreads();  // staged tile visible (drains vmcnt)

    if (k0 <= wrow + 31) {  // wave has at least one unmasked column
      // ---- S = Q @ K^T : 32 rows x 64 cols ----
      floatx4 sacc[2][4] = {};
#pragma unroll
      for (int ks = 0; ks < 4; ks++) {
        short8 bk[4];
#pragma unroll
        for (int nt = 0; nt < 4; nt++) {
          int n = nt * 16 + lc;
          bk[nt] = *(const short8*)&Ks[n * 128 + (((ks * 4 + quad) ^ (n & 15)) * 8)];
        }
#pragma unroll
        for (int pm = 0; pm < 2; pm++)
#pragma unroll
          for (int nt = 0; nt < 4; nt++)
            sacc[pm][nt] = __builtin_amdgcn_mfma_f32_16x16x32_bf16(aq[pm][ks], bk[nt], sacc[pm][nt], 0, 0, 0);
      }

      // ---- causal mask + row max ----
      float mx[2][4];
#pragma unroll
      for (int pm = 0; pm < 2; pm++)
#pragma unroll
        for (int r = 0; r < 4; r++) mx[pm][r] = -1e30f;
      if (k0 + 63 > wrow) {  // diagonal tile: mask needed
#pragma unroll
        for (int pm = 0; pm < 2; pm++)
#pragma unroll
          for (int nt = 0; nt < 4; nt++) {
            int col = k0 + nt * 16 + lc;
#pragma unroll
            for (int r = 0; r < 4; r++) {
              if (col > wrow + pm * 16 + quad * 4 + r) sacc[pm][nt][r] = -1e30f;
              mx[pm][r] = fmaxf(mx[pm][r], sacc[pm][nt][r]);
            }
          }
      } else {
#pragma unroll
        for (int pm = 0; pm < 2; pm++)
#pragma unroll
          for (int nt = 0; nt < 4; nt++)
#pragma unroll
            for (int r = 0; r < 4; r++) mx[pm][r] = fmaxf(mx[pm][r], sacc[pm][nt][r]);
      }
#pragma unroll
      for (int off = 1; off < 16; off <<= 1)
#pragma unroll
        for (int pm = 0; pm < 2; pm++)
#pragma unroll
          for (int r = 0; r < 4; r++) mx[pm][r] = fmaxf(mx[pm][r], __shfl_xor(mx[pm][r], off));

      // ---- online stats; P = exp(S-m) -> LDS (swizzled, own rows); lane-partial sums ----
      float alpha[2][4];
#pragma unroll
      for (int pm = 0; pm < 2; pm++)
#pragma unroll
        for (int r = 0; r < 4; r++) {
          float mnew = fmaxf(m_run[pm][r], mx[pm][r]);
          alpha[pm][r] = __expf(m_run[pm][r] - mnew);
          m_run[pm][r] = mnew;
          l_run[pm][r] *= alpha[pm][r];
        }
#pragma unroll
      for (int pm = 0; pm < 2; pm++)
#pragma unroll
        for (int nt = 0; nt < 4; nt++) {
          int chs = ((nt * 2 + (lc >> 3)) * 8) + (lc & 7);  // chunk base + within-chunk
#pragma unroll
          for (int r = 0; r < 4; r++) {
            float p = __expf(sacc[pm][nt][r] - m_run[pm][r]);
            l_run[pm][r] += p;
            int row = w * 32 + pm * 16 + quad * 4 + r;
            int sw = (((nt * 2 + (lc >> 3)) ^ (row & 7)) * 8) + (lc & 7);
            Ps[row * 64 + sw] = f2b(p);
          }
          (void)chs;
        }

      // ---- rescale O ----
#pragma unroll
      for (int pm = 0; pm < 2; pm++)
#pragma unroll
        for (int nt8 = 0; nt8 < 8; nt8++)
#pragma unroll
          for (int r = 0; r < 4; r++) oacc[pm][nt8][r] *= alpha[pm][r];

      // ---- O += P @ V (A from own Ps rows — same-wave ordering, no barrier) ----
#pragma unroll
      for (int ks = 0; ks < 2; ks++) {
        short8 ap[2];
#pragma unroll
        for (int pm = 0; pm < 2; pm++) {
          int m = w * 32 + pm * 16 + lc;
          ap[pm] = *(const short8*)&Ps[m * 64 + (((ks * 4 + quad) ^ (m & 7)) * 8)];
        }
#pragma unroll
        for (int nt8 = 0; nt8 < 8; nt8++) {
          int n = nt8 * 16 + lc;
          short8 bv = *(const short8*)&Vs[n * 64 + (((ks * 4 + quad) ^ (n & 7)) * 8)];
#pragma unroll
          for (int pm = 0; pm < 2; pm++)
            oacc[pm][nt8] = __builtin_amdgcn_mfma_f32_16x16x32_bf16(ap[pm], bv, oacc[pm][nt8], 0, 0, 0);
        }
      }
    }
  }

  // final row-sum reduce (deferred), then O /= l, write bf16 [b,s,h,hd]
#pragma unroll
  for (int off = 1; off < 16; off <<= 1)
#pragma unroll
    for (int pm = 0; pm < 2; pm++)
#pragma unroll
      for (int r = 0; r < 4; r++) l_run[pm][r] += __shfl_xor(l_run[pm][r], off);
#pragma unroll
  for (int pm = 0; pm < 2; pm++)
#pragma unroll
    for (int r = 0; r < 4; r++) {
      float inv = 1.f / l_run[pm][r];
      size_t obase = ((size_t)(b * S_LEN + wrow + pm * 16 + quad * 4 + r)) * DMODEL + h * HDIM;
#pragma unroll
      for (int nt8 = 0; nt8 < 8; nt8++)
        Og[obase + nt8 * 16 + lc] = f2b(oacc[pm][nt8][r] * inv);
    }
}

// ---------------- launch ----------------
extern "C" void kernel_launch(void* const* d_in, const int* in_sizes, int n_in,
                              void* d_out, int out_size, void* d_ws, size_t ws_size,
                              hipStream_t stream) {
  const float* x  = (const float*)d_in[0];
  const float* Wq = (const float*)d_in[1];
  const float* bq = (const float*)d_in[2];
  const float* Wk = (const float*)d_in[3];
  const float* bk = (const float*)d_in[4];
  const float* Wv = (const float*)d_in[5];
  const float* bv = (const float*)d_in[6];
  const float* Wo = (const float*)d_in[7];
  const float* bo = (const float*)d_in[8];

  const int M = 2 * S_LEN;  // 4096
  const int N = DMODEL, K = DMODEL;

  char* w = (char*)d_ws;  // needs 112 MB
  unsigned short* xb  = (unsigned short*)(w);
  unsigned short* Wqb = (unsigned short*)(w + (size_t)16 * (1 << 20));
  unsigned short* Wkb = (unsigned short*)(w + (size_t)24 * (1 << 20));
  unsigned short* Wvb = (unsigned short*)(w + (size_t)32 * (1 << 20));
  unsigned short* Wob = (unsigned short*)(w + (size_t)40 * (1 << 20));
  unsigned short* Qb  = (unsigned short*)(w + (size_t)48 * (1 << 20));
  unsigned short* Kb  = (unsigned short*)(w + (size_t)64 * (1 << 20));
  unsigned short* Vtb = (unsigned short*)(w + (size_t)80 * (1 << 20));
  unsigned short* Ob  = (unsigned short*)(w + (size_t)96 * (1 << 20));

  cvt_all<<<dim3(4096, 6), 256, 0, stream>>>(x, Wq, Wk, Wv, Wo, xb, Wqb, Wkb, Wvb, Wob);

  dim3 gg(N / 128, M / 128);
  const float qscale = 0.08838834764831843f;  // 1/sqrt(128), applied after bias like ref
  gemm_bt<0><<<gg, 256, 0, stream>>>(xb, Wqb, bq, Qb, M, N, K, qscale);
  gemm_bt<0><<<gg, 256, 0, stream>>>(xb, Wkb, bk, Kb, M, N, K, 1.f);
  gemm_bt<1><<<gg, 256, 0, stream>>>(xb, Wvb, bv, Vtb, M, N, K, 1.f);

  attn_fwd<<<dim3(16, 32), 256, 0, stream>>>(Qb, Kb, Vtb, Ob);

  gemm_bt<2><<<gg, 256, 0, stream>>>(Ob, Wob, bo, d_out, M, N, K, 1.f);
}

// Round 5
// 396.454 us; speedup vs baseline: 1.4308x; 1.0373x over previous
//
#include <hip/hip_runtime.h>
#include <stdint.h>

// Problem constants (B=2, S=2048, D=2048, H=16, HD=128)
#define S_LEN 2048
#define DMODEL 2048
#define NHEAD 16
#define HDIM 128

typedef __attribute__((ext_vector_type(8))) short short8;   // 8 bf16 (4 VGPRs)
typedef __attribute__((ext_vector_type(4))) float floatx4;  // MFMA acc

__device__ __forceinline__ unsigned short f2b(float f) {
  union { float f; unsigned u; } v; v.f = f;
  unsigned r = v.u + 0x7FFFu + ((v.u >> 16) & 1u);  // RNE
  return (unsigned short)(r >> 16);
}

// async global->LDS, 16B per lane; LDS dest is wave-uniform base + lane*16
__device__ __forceinline__ void load_lds16(const unsigned short* g, unsigned short* l) {
  __builtin_amdgcn_global_load_lds((const __attribute__((address_space(1))) void*)g,
                                   (__attribute__((address_space(3))) void*)l, 16, 0, 0);
}

// ---------------- fused fp32 -> bf16 conversion (x in 2 slices + 4 weights) ----------------
__global__ __launch_bounds__(256) void cvt_all(const float* __restrict__ x,
                                               const float* __restrict__ Wq, const float* __restrict__ Wk,
                                               const float* __restrict__ Wv, const float* __restrict__ Wo,
                                               unsigned short* __restrict__ xb,
                                               unsigned short* __restrict__ Wqb, unsigned short* __restrict__ Wkb,
                                               unsigned short* __restrict__ Wvb, unsigned short* __restrict__ Wob) {
  const size_t idx = (size_t)blockIdx.x * 256 + threadIdx.x;  // < 2^20 per slice
  const int y = blockIdx.y;
  const float4* s; ushort4* d;
  if (y == 0)      { s = (const float4*)x;               d = (ushort4*)xb; }
  else if (y == 1) { s = (const float4*)x + (1u << 20);  d = (ushort4*)xb + (1u << 20); }
  else if (y == 2) { s = (const float4*)Wq;              d = (ushort4*)Wqb; }
  else if (y == 3) { s = (const float4*)Wk;              d = (ushort4*)Wkb; }
  else if (y == 4) { s = (const float4*)Wv;              d = (ushort4*)Wvb; }
  else             { s = (const float4*)Wo;              d = (ushort4*)Wob; }
  float4 f = s[idx];
  ushort4 o;
  o.x = f2b(f.x); o.y = f2b(f.y); o.z = f2b(f.z); o.w = f2b(f.w);
  d[idx] = o;
}

// ---------------- GEMM: C = A @ Bw^T + bias, A:[M,K] bf16, Bw:[N,K] bf16 ----------------
// m97-style: global_load_lds width=16 staging into unpadded [128][64] LDS tiles with
// XOR k-chunk swizzle (LDS[row][slot] = G[row][slot ^ (row&7)]) for bank spread.
// MODE 0: bf16 row-major out [M,N];  MODE 1: bf16 V-transposed out [(b*D+col)*S + s];
// MODE 2: fp32 row-major out.
template <int MODE>
__global__ __launch_bounds__(256)
void gemm_bt(const unsigned short* __restrict__ A, const unsigned short* __restrict__ Bw,
             const float* __restrict__ bias, void* __restrict__ Cout,
             int M, int N, int K, float scale) {
  __shared__ unsigned short As[128 * 64];  // 16 KB, NO padding (global_load_lds constraint)
  __shared__ unsigned short Bs[128 * 64];
  const int t = threadIdx.x;
  const int lane = t & 63, wave = t >> 6;
  const int quad = lane >> 4, lc = lane & 15;
  const int wm = wave >> 1, wn = wave & 1;  // 2x2 waves, 64x64 per wave
  const int m0 = blockIdx.y * 128, n0 = blockIdx.x * 128;

  // staging geometry: chunk c = wave*4+i covers rows c*8..c*8+8; lane covers
  // row c*8+(lane>>3), global k-chunk ((lane&7) ^ (lane>>3)) (XOR swizzle)
  const int srow = lane >> 3;
  const int skoff = ((lane & 7) ^ srow) * 8;
  const unsigned short* Ag[4];
  const unsigned short* Bg[4];
  unsigned short* Al[4];
  unsigned short* Bl[4];
#pragma unroll
  for (int i = 0; i < 4; i++) {
    int c = wave * 4 + i;
    Ag[i] = A + (size_t)(m0 + c * 8 + srow) * K + skoff;
    Bg[i] = Bw + (size_t)(n0 + c * 8 + srow) * K + skoff;
    Al[i] = &As[c * 512 + lane * 8];
    Bl[i] = &Bs[c * 512 + lane * 8];
  }

  // fragment-read swizzled k offsets (elements): want global chunk ks*4+quad at row r
  // -> LDS slot (ks*4+quad) ^ (r&7); our rows have r&7 == lc&7
  int koff[2];
#pragma unroll
  for (int ks = 0; ks < 2; ks++) koff[ks] = ((ks * 4 + quad) ^ (lc & 7)) * 8;

  floatx4 acc[4][4] = {};

  for (int kt = 0; kt < K; kt += 64) {
    if (kt) __syncthreads();  // protect LDS from overwrite while prior reads in flight
#pragma unroll
    for (int i = 0; i < 4; i++) {
      load_lds16(Ag[i] + kt, Al[i]);
      load_lds16(Bg[i] + kt, Bl[i]);
    }
    __syncthreads();  // drains vmcnt(0): staged tile visible
#pragma unroll
    for (int ks = 0; ks < 2; ks++) {
      short8 av[4], bv[4];
#pragma unroll
      for (int mt = 0; mt < 4; mt++)
        av[mt] = *(const short8*)&As[(wm * 64 + mt * 16 + lc) * 64 + koff[ks]];
#pragma unroll
      for (int nt = 0; nt < 4; nt++)
        bv[nt] = *(const short8*)&Bs[(wn * 64 + nt * 16 + lc) * 64 + koff[ks]];
#pragma unroll
      for (int mt = 0; mt < 4; mt++)
#pragma unroll
        for (int nt = 0; nt < 4; nt++)
          acc[mt][nt] = __builtin_amdgcn_mfma_f32_16x16x32_bf16(av[mt], bv[nt], acc[mt][nt], 0, 0, 0);
    }
  }

#pragma unroll
  for (int nt = 0; nt < 4; nt++) {
    const int col = n0 + wn * 64 + nt * 16 + lc;
    const float bcol = bias[col];
#pragma unroll
    for (int mt = 0; mt < 4; mt++) {
      const int row0 = m0 + wm * 64 + mt * 16 + quad * 4;
      if (MODE == 1) {
        // V^T layout: out[(b*D + col)*S + s], 4 consecutive s per lane -> one 8B store
        ushort4 o;
        o.x = f2b((acc[mt][nt][0] + bcol) * scale);
        o.y = f2b((acc[mt][nt][1] + bcol) * scale);
        o.z = f2b((acc[mt][nt][2] + bcol) * scale);
        o.w = f2b((acc[mt][nt][3] + bcol) * scale);
        int b = row0 >> 11;            // row0 / S_LEN
        int s = row0 & (S_LEN - 1);
        *(ushort4*)&((unsigned short*)Cout)[((size_t)(b * DMODEL + col)) * S_LEN + s] = o;
      } else {
#pragma unroll
        for (int r = 0; r < 4; r++) {
          float v = (acc[mt][nt][r] + bcol) * scale;
          if (MODE == 2)
            ((float*)Cout)[(size_t)(row0 + r) * N + col] = v;
          else
            ((unsigned short*)Cout)[(size_t)(row0 + r) * N + col] = f2b(v);
        }
      }
    }
  }
}

// ---------------- Flash attention (causal), BM=128, software-pipelined K-loop ----------------
// Q,K: [b,s,h,hd] rows of [B*S, D]; Vt: [b,h,hd,s]; O: [b,s,h,hd].
// Q pre-scaled by log2(e)/sqrt(HD) so softmax uses exp2 directly.
// Pipeline per iter: __syncthreads (drains K(kb) prefetch from prev iter) ->
//   issue V(kb) + K(kb+1) async -> QK/softmax on K[cur] ->
//   "s_waitcnt vmcnt(4); s_barrier" (V landed; K prefetch stays in flight) -> PV.
// K prefetch issued unconditionally (clamped on last iter) so outstanding==8 at the mid-wait.
__global__ __launch_bounds__(256, 2)
void attn_fwd(const unsigned short* __restrict__ Qg, const unsigned short* __restrict__ Kg,
              const unsigned short* __restrict__ Vtg, unsigned short* __restrict__ Og) {
  __shared__ unsigned short Ks[2][64 * 128];  // 32 KB [buf][krow][chunk^(krow&15)]
  __shared__ unsigned short Vs[128 * 64];     // 16 KB [hd][chunk^(hd&7)]
  __shared__ unsigned short Ps[128 * 64];     // 16 KB [qrow][chunk^(qrow&7)]  -> 64 KB total

  const int t = threadIdx.x;
  const int lane = t & 63, w = t >> 6;
  const int quad = lane >> 4, lc = lane & 15;
  const int y = blockIdx.y;
  const int tile = (y < 16) ? (int)blockIdx.x : 15 - (int)blockIdx.x;
  const int b = y >> 4, h = y & 15;
  const size_t qkbase = (size_t)b * S_LEN * DMODEL + h * HDIM;
  const size_t vtbase = ((size_t)(b * DMODEL + h * HDIM)) * S_LEN;
  const int q0 = tile * 128;
  const int wrow = q0 + w * 32;  // wave's first q-row

  // Q A-frags in registers: rows wrow + pm*16 + lc, k = ks*32 + quad*8
  short8 aq[2][4];
#pragma unroll
  for (int pm = 0; pm < 2; pm++)
#pragma unroll
    for (int ks = 0; ks < 4; ks++)
      aq[pm][ks] = *(const short8*)&Qg[qkbase + (size_t)(wrow + pm * 16 + lc) * DMODEL + ks * 32 + quad * 8];

  // staging pointers (chunk c = w*4+i)
  const unsigned short* kga[4];
  const unsigned short* vga[4];
  int kloff[4], vloff[4];
#pragma unroll
  for (int i = 0; i < 4; i++) {
    int c = w * 4 + i;
    int krow = 4 * c + (lane >> 4);
    kga[i] = Kg + qkbase + (size_t)krow * DMODEL + ((lane & 15) ^ (krow & 15)) * 8;
    kloff[i] = c * 512 + lane * 8;
    int vrow = 8 * c + (lane >> 3);
    vga[i] = Vtg + vtbase + (size_t)vrow * S_LEN + ((lane & 7) ^ (vrow & 7)) * 8;
    vloff[i] = c * 512 + lane * 8;
  }

  floatx4 oacc[2][8] = {};
  float m_run[2][4], l_run[2][4];
#pragma unroll
  for (int pm = 0; pm < 2; pm++)
#pragma unroll
    for (int r = 0; r < 4; r++) { m_run[pm][r] = -1e30f; l_run[pm][r] = 0.f; }

  const int kiters = 2 * tile + 2;

  // prologue: K(0) into buf 0
#pragma unroll
  for (int i = 0; i < 4; i++) load_lds16(kga[i], &Ks[0][kloff[i]]);

  for (int kb = 0; kb < kiters; kb++) {
    const int k0 = kb * 64;
    const int cur = kb & 1;
    __syncthreads();  // drains K(kb) prefetch; fences PV(kb-1) reads of Vs/Ps

    // issue V(kb) (oldest 4) then K(kb+1) prefetch (clamped on last iter; 8 outstanding)
#pragma unroll
    for (int i = 0; i < 4; i++) load_lds16(vga[i] + k0, &Vs[vloff[i]]);
    {
      const size_t knext = (size_t)((kb + 1 < kiters) ? k0 + 64 : k0) * DMODEL;
#pragma unroll
      for (int i = 0; i < 4; i++) load_lds16(kga[i] + knext, &Ks[cur ^ 1][kloff[i]]);
    }

    const bool hasw = (k0 <= wrow + 31);  // wave has at least one unmasked column
    floatx4 sacc[2][4];
    float alpha[2][4];
    if (hasw) {
      // ---- S = Q @ K^T : 32 rows x 64 cols ----
#pragma unroll
      for (int pm = 0; pm < 2; pm++)
#pragma unroll
        for (int nt = 0; nt < 4; nt++) sacc[pm][nt] = (floatx4){0.f, 0.f, 0.f, 0.f};
#pragma unroll
      for (int ks = 0; ks < 4; ks++) {
        short8 bk[4];
#pragma unroll
        for (int nt = 0; nt < 4; nt++) {
          int n = nt * 16 + lc;
          bk[nt] = *(const short8*)&Ks[cur][n * 128 + (((ks * 4 + quad) ^ (n & 15)) * 8)];
        }
#pragma unroll
        for (int pm = 0; pm < 2; pm++)
#pragma unroll
          for (int nt = 0; nt < 4; nt++)
            sacc[pm][nt] = __builtin_amdgcn_mfma_f32_16x16x32_bf16(aq[pm][ks], bk[nt], sacc[pm][nt], 0, 0, 0);
      }

      // ---- causal mask + row max (values are in log2 domain) ----
      float mx[2][4];
#pragma unroll
      for (int pm = 0; pm < 2; pm++)
#pragma unroll
        for (int r = 0; r < 4; r++) mx[pm][r] = -1e30f;
      if (k0 + 63 > wrow) {  // diagonal tile: mask needed
#pragma unroll
        for (int pm = 0; pm < 2; pm++)
#pragma unroll
          for (int nt = 0; nt < 4; nt++) {
            int col = k0 + nt * 16 + lc;
#pragma unroll
            for (int r = 0; r < 4; r++) {
              if (col > wrow + pm * 16 + quad * 4 + r) sacc[pm][nt][r] = -1e30f;
              mx[pm][r] = fmaxf(mx[pm][r], sacc[pm][nt][r]);
            }
          }
      } else {
#pragma unroll
        for (int pm = 0; pm < 2; pm++)
#pragma unroll
          for (int nt = 0; nt < 4; nt++)
#pragma unroll
            for (int r = 0; r < 4; r++) mx[pm][r] = fmaxf(mx[pm][r], sacc[pm][nt][r]);
      }
#pragma unroll
      for (int off = 1; off < 16; off <<= 1)
#pragma unroll
        for (int pm = 0; pm < 2; pm++)
#pragma unroll
          for (int r = 0; r < 4; r++) mx[pm][r] = fmaxf(mx[pm][r], __shfl_xor(mx[pm][r], off));

      // ---- online stats; P = exp2(S-m) -> LDS (swizzled, own rows); lane-partial sums ----
#pragma unroll
      for (int pm = 0; pm < 2; pm++)
#pragma unroll
        for (int r = 0; r < 4; r++) {
          float mnew = fmaxf(m_run[pm][r], mx[pm][r]);
          alpha[pm][r] = __builtin_amdgcn_exp2f(m_run[pm][r] - mnew);
          m_run[pm][r] = mnew;
          l_run[pm][r] *= alpha[pm][r];
        }
#pragma unroll
      for (int pm = 0; pm < 2; pm++)
#pragma unroll
        for (int nt = 0; nt < 4; nt++) {
#pragma unroll
          for (int r = 0; r < 4; r++) {
            float p = __builtin_amdgcn_exp2f(sacc[pm][nt][r] - m_run[pm][r]);
            l_run[pm][r] += p;
            int row = w * 32 + pm * 16 + quad * 4 + r;
            int sw = (((nt * 2 + (lc >> 3)) ^ (row & 7)) * 8) + (lc & 7);
            Ps[row * 64 + sw] = f2b(p);
          }
        }
    }

    // V(kb) landed (oldest 4 of 8); K(kb+1) prefetch stays in flight across this barrier.
    // ALL waves execute this (barrier counts must match across waves).
    asm volatile("s_waitcnt vmcnt(4)\n\ts_barrier" ::: "memory");

    if (hasw) {
      // ---- rescale O ----
#pragma unroll
      for (int pm = 0; pm < 2; pm++)
#pragma unroll
        for (int nt8 = 0; nt8 < 8; nt8++)
#pragma unroll
          for (int r = 0; r < 4; r++) oacc[pm][nt8][r] *= alpha[pm][r];

      // ---- O += P @ V (A from own Ps rows — same-wave ordering) ----
#pragma unroll
      for (int ks = 0; ks < 2; ks++) {
        short8 ap[2];
#pragma unroll
        for (int pm = 0; pm < 2; pm++) {
          int m = w * 32 + pm * 16 + lc;
          ap[pm] = *(const short8*)&Ps[m * 64 + (((ks * 4 + quad) ^ (m & 7)) * 8)];
        }
#pragma unroll
        for (int nt8 = 0; nt8 < 8; nt8++) {
          int n = nt8 * 16 + lc;
          short8 bv = *(const short8*)&Vs[n * 64 + (((ks * 4 + quad) ^ (n & 7)) * 8)];
#pragma unroll
          for (int pm = 0; pm < 2; pm++)
            oacc[pm][nt8] = __builtin_amdgcn_mfma_f32_16x16x32_bf16(ap[pm], bv, oacc[pm][nt8], 0, 0, 0);
        }
      }
    }
  }

  // final row-sum reduce (deferred), then O /= l, write bf16 [b,s,h,hd]
#pragma unroll
  for (int off = 1; off < 16; off <<= 1)
#pragma unroll
    for (int pm = 0; pm < 2; pm++)
#pragma unroll
      for (int r = 0; r < 4; r++) l_run[pm][r] += __shfl_xor(l_run[pm][r], off);
#pragma unroll
  for (int pm = 0; pm < 2; pm++)
#pragma unroll
    for (int r = 0; r < 4; r++) {
      float inv = 1.f / l_run[pm][r];
      size_t obase = ((size_t)(b * S_LEN + wrow + pm * 16 + quad * 4 + r)) * DMODEL + h * HDIM;
#pragma unroll
      for (int nt8 = 0; nt8 < 8; nt8++)
        Og[obase + nt8 * 16 + lc] = f2b(oacc[pm][nt8][r] * inv);
    }
}

// ---------------- launch ----------------
extern "C" void kernel_launch(void* const* d_in, const int* in_sizes, int n_in,
                              void* d_out, int out_size, void* d_ws, size_t ws_size,
                              hipStream_t stream) {
  const float* x  = (const float*)d_in[0];
  const float* Wq = (const float*)d_in[1];
  const float* bq = (const float*)d_in[2];
  const float* Wk = (const float*)d_in[3];
  const float* bk = (const float*)d_in[4];
  const float* Wv = (const float*)d_in[5];
  const float* bv = (const float*)d_in[6];
  const float* Wo = (const float*)d_in[7];
  const float* bo = (const float*)d_in[8];

  const int M = 2 * S_LEN;  // 4096
  const int N = DMODEL, K = DMODEL;

  char* w = (char*)d_ws;  // needs 112 MB
  unsigned short* xb  = (unsigned short*)(w);
  unsigned short* Wqb = (unsigned short*)(w + (size_t)16 * (1 << 20));
  unsigned short* Wkb = (unsigned short*)(w + (size_t)24 * (1 << 20));
  unsigned short* Wvb = (unsigned short*)(w + (size_t)32 * (1 << 20));
  unsigned short* Wob = (unsigned short*)(w + (size_t)40 * (1 << 20));
  unsigned short* Qb  = (unsigned short*)(w + (size_t)48 * (1 << 20));
  unsigned short* Kb  = (unsigned short*)(w + (size_t)64 * (1 << 20));
  unsigned short* Vtb = (unsigned short*)(w + (size_t)80 * (1 << 20));
  unsigned short* Ob  = (unsigned short*)(w + (size_t)96 * (1 << 20));

  cvt_all<<<dim3(4096, 6), 256, 0, stream>>>(x, Wq, Wk, Wv, Wo, xb, Wqb, Wkb, Wvb, Wob);

  dim3 gg(N / 128, M / 128);
  // Q scale: log2(e)/sqrt(128) so attention softmax can use exp2 directly
  const float qscale = 0.08838834764831843f * 1.4426950408889634f;
  gemm_bt<0><<<gg, 256, 0, stream>>>(xb, Wqb, bq, Qb, M, N, K, qscale);
  gemm_bt<0><<<gg, 256, 0, stream>>>(xb, Wkb, bk, Kb, M, N, K, 1.f);
  gemm_bt<1><<<gg, 256, 0, stream>>>(xb, Wvb, bv, Vtb, M, N, K, 1.f);

  attn_fwd<<<dim3(16, 32), 256, 0, stream>>>(Qb, Kb, Vtb, Ob);

  gemm_bt<2><<<gg, 256, 0, stream>>>(Ob, Wob, bo, d_out, M, N, K, 1.f);
}

// Round 6
// 379.440 us; speedup vs baseline: 1.4949x; 1.0448x over previous
//
#include <hip/hip_runtime.h>
#include <stdint.h>

// Problem constants (B=2, S=2048, D=2048, H=16, HD=128)
#define S_LEN 2048
#define DMODEL 2048
#define NHEAD 16
#define HDIM 128

typedef __attribute__((ext_vector_type(8))) short short8;   // 8 bf16 (4 VGPRs)
typedef __attribute__((ext_vector_type(4))) float floatx4;  // MFMA acc

__device__ __forceinline__ unsigned short f2b(float f) {
  union { float f; unsigned u; } v; v.f = f;
  unsigned r = v.u + 0x7FFFu + ((v.u >> 16) & 1u);  // RNE
  return (unsigned short)(r >> 16);
}

// async global->LDS, 16B per lane; LDS dest is wave-uniform base + lane*16
__device__ __forceinline__ void load_lds16(const unsigned short* g, unsigned short* l) {
  __builtin_amdgcn_global_load_lds((const __attribute__((address_space(1))) void*)g,
                                   (__attribute__((address_space(3))) void*)l, 16, 0, 0);
}

// ---------------- fused fp32 -> bf16 conversion (x in 2 slices + 4 weights) ----------------
__global__ __launch_bounds__(256) void cvt_all(const float* __restrict__ x,
                                               const float* __restrict__ Wq, const float* __restrict__ Wk,
                                               const float* __restrict__ Wv, const float* __restrict__ Wo,
                                               unsigned short* __restrict__ xb,
                                               unsigned short* __restrict__ Wqb, unsigned short* __restrict__ Wkb,
                                               unsigned short* __restrict__ Wvb, unsigned short* __restrict__ Wob) {
  const size_t idx = (size_t)blockIdx.x * 256 + threadIdx.x;  // < 2^20 per slice
  const int y = blockIdx.y;
  const float4* s; ushort4* d;
  if (y == 0)      { s = (const float4*)x;               d = (ushort4*)xb; }
  else if (y == 1) { s = (const float4*)x + (1u << 20);  d = (ushort4*)xb + (1u << 20); }
  else if (y == 2) { s = (const float4*)Wq;              d = (ushort4*)Wqb; }
  else if (y == 3) { s = (const float4*)Wk;              d = (ushort4*)Wkb; }
  else if (y == 4) { s = (const float4*)Wv;              d = (ushort4*)Wvb; }
  else             { s = (const float4*)Wo;              d = (ushort4*)Wob; }
  float4 f = s[idx];
  ushort4 o;
  o.x = f2b(f.x); o.y = f2b(f.y); o.z = f2b(f.z); o.w = f2b(f.w);
  d[idx] = o;
}

// ---------------- GEMM: C = A @ Bw^T + bias, A:[M,K] bf16, Bw:[N,K] bf16 ----------------
// m97-style: global_load_lds width=16 staging into unpadded [128][64] LDS tiles with
// XOR k-chunk swizzle (LDS[row][slot] = G[row][slot ^ (row&7)]) for bank spread.
// MODE 0: bf16 row-major out [M,N];  MODE 1: bf16 V-transposed out [(b*D+col)*S + s];
// MODE 2: fp32 row-major out.
template <int MODE>
__global__ __launch_bounds__(256)
void gemm_bt(const unsigned short* __restrict__ A, const unsigned short* __restrict__ Bw,
             const float* __restrict__ bias, void* __restrict__ Cout,
             int M, int N, int K, float scale) {
  __shared__ unsigned short As[128 * 64];  // 16 KB, NO padding (global_load_lds constraint)
  __shared__ unsigned short Bs[128 * 64];
  const int t = threadIdx.x;
  const int lane = t & 63, wave = t >> 6;
  const int quad = lane >> 4, lc = lane & 15;
  const int wm = wave >> 1, wn = wave & 1;  // 2x2 waves, 64x64 per wave
  const int m0 = blockIdx.y * 128, n0 = blockIdx.x * 128;

  // staging geometry: chunk c = wave*4+i covers rows c*8..c*8+8; lane covers
  // row c*8+(lane>>3), global k-chunk ((lane&7) ^ (lane>>3)) (XOR swizzle)
  const int srow = lane >> 3;
  const int skoff = ((lane & 7) ^ srow) * 8;
  const unsigned short* Ag[4];
  const unsigned short* Bg[4];
  unsigned short* Al[4];
  unsigned short* Bl[4];
#pragma unroll
  for (int i = 0; i < 4; i++) {
    int c = wave * 4 + i;
    Ag[i] = A + (size_t)(m0 + c * 8 + srow) * K + skoff;
    Bg[i] = Bw + (size_t)(n0 + c * 8 + srow) * K + skoff;
    Al[i] = &As[c * 512 + lane * 8];
    Bl[i] = &Bs[c * 512 + lane * 8];
  }

  // fragment-read swizzled k offsets (elements): want global chunk ks*4+quad at row r
  // -> LDS slot (ks*4+quad) ^ (r&7); our rows have r&7 == lc&7
  int koff[2];
#pragma unroll
  for (int ks = 0; ks < 2; ks++) koff[ks] = ((ks * 4 + quad) ^ (lc & 7)) * 8;

  floatx4 acc[4][4] = {};

  for (int kt = 0; kt < K; kt += 64) {
    if (kt) __syncthreads();  // protect LDS from overwrite while prior reads in flight
#pragma unroll
    for (int i = 0; i < 4; i++) {
      load_lds16(Ag[i] + kt, Al[i]);
      load_lds16(Bg[i] + kt, Bl[i]);
    }
    __syncthreads();  // drains vmcnt(0): staged tile visible
#pragma unroll
    for (int ks = 0; ks < 2; ks++) {
      short8 av[4], bv[4];
#pragma unroll
      for (int mt = 0; mt < 4; mt++)
        av[mt] = *(const short8*)&As[(wm * 64 + mt * 16 + lc) * 64 + koff[ks]];
#pragma unroll
      for (int nt = 0; nt < 4; nt++)
        bv[nt] = *(const short8*)&Bs[(wn * 64 + nt * 16 + lc) * 64 + koff[ks]];
#pragma unroll
      for (int mt = 0; mt < 4; mt++)
#pragma unroll
        for (int nt = 0; nt < 4; nt++)
          acc[mt][nt] = __builtin_amdgcn_mfma_f32_16x16x32_bf16(av[mt], bv[nt], acc[mt][nt], 0, 0, 0);
    }
  }

#pragma unroll
  for (int nt = 0; nt < 4; nt++) {
    const int col = n0 + wn * 64 + nt * 16 + lc;
    const float bcol = bias[col];
#pragma unroll
    for (int mt = 0; mt < 4; mt++) {
      const int row0 = m0 + wm * 64 + mt * 16 + quad * 4;
      if (MODE == 1) {
        // V^T layout: out[(b*D + col)*S + s], 4 consecutive s per lane -> one 8B store
        ushort4 o;
        o.x = f2b((acc[mt][nt][0] + bcol) * scale);
        o.y = f2b((acc[mt][nt][1] + bcol) * scale);
        o.z = f2b((acc[mt][nt][2] + bcol) * scale);
        o.w = f2b((acc[mt][nt][3] + bcol) * scale);
        int b = row0 >> 11;            // row0 / S_LEN
        int s = row0 & (S_LEN - 1);
        *(ushort4*)&((unsigned short*)Cout)[((size_t)(b * DMODEL + col)) * S_LEN + s] = o;
      } else {
#pragma unroll
        for (int r = 0; r < 4; r++) {
          float v = (acc[mt][nt][r] + bcol) * scale;
          if (MODE == 2)
            ((float*)Cout)[(size_t)(row0 + r) * N + col] = v;
          else
            ((unsigned short*)Cout)[(size_t)(row0 + r) * N + col] = f2b(v);
        }
      }
    }
  }
}

// ---------------- Flash attention (causal), BM=128, S^T orientation ----------------
// Q,K: [b,s,h,hd] rows of [B*S, D]; Vt: [b,h,hd,s]; O: [b,s,h,hd].
// Q pre-scaled by log2(e)/sqrt(HD) so softmax uses exp2.
// Computes S^T = mfma(K-frag, Q-frag) (same registers as before, swapped operands):
// lane holds one query (lc) x 16 keys -> in-lane max, 2-shuffle row reduce, b64 P writes.
// PV as O^T = mfma(V^T-frag, P^T-frag). Pipeline: K double-buffered, V single with
// mid-loop "s_waitcnt vmcnt(4); s_barrier" (K prefetch never drained mid-loop).
__global__ __launch_bounds__(256, 2)
void attn_fwd(const unsigned short* __restrict__ Qg, const unsigned short* __restrict__ Kg,
              const unsigned short* __restrict__ Vtg, unsigned short* __restrict__ Og) {
  __shared__ unsigned short Ks[2][64 * 128];  // 32 KB [buf][krow][chunk^(krow&15)]
  __shared__ unsigned short Vs[128 * 64];     // 16 KB [hd][chunk^(hd&7)]
  __shared__ unsigned short Ps[128 * 72];     // 18 KB [query][key], pitch 72 spreads banks

  const int t = threadIdx.x;
  const int lane = t & 63, w = t >> 6;
  const int quad = lane >> 4, lc = lane & 15;
  const int y = blockIdx.y;
  const int tile = (y < 16) ? (int)blockIdx.x : 15 - (int)blockIdx.x;
  const int b = y >> 4, h = y & 15;
  const size_t qkbase = (size_t)b * S_LEN * DMODEL + h * HDIM;
  const size_t vtbase = ((size_t)(b * DMODEL + h * HDIM)) * S_LEN;
  const int q0 = tile * 128;
  const int wrow = q0 + w * 32;  // wave's first q-row

  // Q frags in registers: rows wrow + pm*16 + lc, k = ks*32 + quad*8
  // (serves as A-frag of Q and, identically, B-frag of Q^T)
  short8 aq[2][4];
#pragma unroll
  for (int pm = 0; pm < 2; pm++)
#pragma unroll
    for (int ks = 0; ks < 4; ks++)
      aq[pm][ks] = *(const short8*)&Qg[qkbase + (size_t)(wrow + pm * 16 + lc) * DMODEL + ks * 32 + quad * 8];

  // staging pointers (chunk c = w*4+i)
  const unsigned short* kga[4];
  const unsigned short* vga[4];
  int kloff[4], vloff[4];
#pragma unroll
  for (int i = 0; i < 4; i++) {
    int c = w * 4 + i;
    int krow = 4 * c + (lane >> 4);
    kga[i] = Kg + qkbase + (size_t)krow * DMODEL + ((lane & 15) ^ (krow & 15)) * 8;
    kloff[i] = c * 512 + lane * 8;
    int vrow = 8 * c + (lane >> 3);
    vga[i] = Vtg + vtbase + (size_t)vrow * S_LEN + ((lane & 7) ^ (vrow & 7)) * 8;
    vloff[i] = c * 512 + lane * 8;
  }

  floatx4 oaccT[8][2] = {};  // [hd tile mt8][pm]: O^T[hd=mt8*16+quad*4+r][query=pm*16+lc]
  float m_run[2] = {-1e30f, -1e30f}, l_run[2] = {0.f, 0.f};

  const int kiters = 2 * tile + 2;

  // prologue: K(0) into buf 0
#pragma unroll
  for (int i = 0; i < 4; i++) load_lds16(kga[i], &Ks[0][kloff[i]]);

  for (int kb = 0; kb < kiters; kb++) {
    const int k0 = kb * 64;
    const int cur = kb & 1;
    __syncthreads();  // drains K(kb) prefetch; fences PV(kb-1) reads of Vs

    // issue V(kb) (oldest 4) then K(kb+1) prefetch (clamped on last iter; 8 outstanding)
#pragma unroll
    for (int i = 0; i < 4; i++) load_lds16(vga[i] + k0, &Vs[vloff[i]]);
    {
      const size_t knext = (size_t)((kb + 1 < kiters) ? k0 + 64 : k0) * DMODEL;
#pragma unroll
      for (int i = 0; i < 4; i++) load_lds16(kga[i] + knext, &Ks[cur ^ 1][kloff[i]]);
    }

    const bool hasw = (k0 <= wrow + 31);  // wave has at least one unmasked column
    float alpha[2];
    if (hasw) {
      // ---- S^T = K Q^T : 64 keys x 32 queries; st[mt][pm], key=k0+mt*16+quad*4+r, query=pm*16+lc ----
      floatx4 st[4][2];
#pragma unroll
      for (int mt = 0; mt < 4; mt++)
#pragma unroll
        for (int pm = 0; pm < 2; pm++) st[mt][pm] = (floatx4){0.f, 0.f, 0.f, 0.f};
#pragma unroll
      for (int ks = 0; ks < 4; ks++) {
        short8 kf[4];
#pragma unroll
        for (int mt = 0; mt < 4; mt++) {
          int n = mt * 16 + lc;
          kf[mt] = *(const short8*)&Ks[cur][n * 128 + (((ks * 4 + quad) ^ (n & 15)) * 8)];
        }
#pragma unroll
        for (int mt = 0; mt < 4; mt++)
#pragma unroll
          for (int pm = 0; pm < 2; pm++)
            st[mt][pm] = __builtin_amdgcn_mfma_f32_16x16x32_bf16(kf[mt], aq[pm][ks], st[mt][pm], 0, 0, 0);
      }

      // ---- causal mask + per-lane max over this lane's 16 keys ----
      float mx[2] = {-1e30f, -1e30f};
      if (k0 + 63 > wrow) {  // diagonal region: mask needed
#pragma unroll
        for (int pm = 0; pm < 2; pm++) {
          const int qq = wrow + pm * 16 + lc;
#pragma unroll
          for (int mt = 0; mt < 4; mt++) {
            const int key = k0 + mt * 16 + quad * 4;
#pragma unroll
            for (int r = 0; r < 4; r++) {
              if (key + r > qq) st[mt][pm][r] = -1e30f;
              mx[pm] = fmaxf(mx[pm], st[mt][pm][r]);
            }
          }
        }
      } else {
#pragma unroll
        for (int pm = 0; pm < 2; pm++)
#pragma unroll
          for (int mt = 0; mt < 4; mt++)
#pragma unroll
            for (int r = 0; r < 4; r++) mx[pm] = fmaxf(mx[pm], st[mt][pm][r]);
      }
      // row(=query) max: reduce across the 4 quads only (2 shuffles per pm)
#pragma unroll
      for (int pm = 0; pm < 2; pm++) {
        mx[pm] = fmaxf(mx[pm], __shfl_xor(mx[pm], 16));
        mx[pm] = fmaxf(mx[pm], __shfl_xor(mx[pm], 32));
        float mnew = fmaxf(m_run[pm], mx[pm]);
        alpha[pm] = __builtin_amdgcn_exp2f(m_run[pm] - mnew);
        m_run[pm] = mnew;
        l_run[pm] *= alpha[pm];
      }

      // ---- P = exp2(S^T - m): 4 consecutive keys per lane -> b64 writes; lane-partial sums ----
#pragma unroll
      for (int pm = 0; pm < 2; pm++)
#pragma unroll
        for (int mt = 0; mt < 4; mt++) {
          float p0 = __builtin_amdgcn_exp2f(st[mt][pm][0] - m_run[pm]);
          float p1 = __builtin_amdgcn_exp2f(st[mt][pm][1] - m_run[pm]);
          float p2 = __builtin_amdgcn_exp2f(st[mt][pm][2] - m_run[pm]);
          float p3 = __builtin_amdgcn_exp2f(st[mt][pm][3] - m_run[pm]);
          l_run[pm] += (p0 + p1) + (p2 + p3);
          ushort4 o;
          o.x = f2b(p0); o.y = f2b(p1); o.z = f2b(p2); o.w = f2b(p3);
          *(ushort4*)&Ps[(w * 32 + pm * 16 + lc) * 72 + mt * 16 + quad * 4] = o;
        }
    }

    // V(kb) landed (oldest 4 of 8); K(kb+1) prefetch stays in flight across this barrier.
    // ALL waves execute this (barrier counts must match across waves).
    asm volatile("s_waitcnt vmcnt(4)\n\ts_barrier" ::: "memory");

    if (hasw) {
      // ---- rescale O^T (alpha is one scalar per lane per pm) ----
#pragma unroll
      for (int mt8 = 0; mt8 < 8; mt8++)
#pragma unroll
        for (int pm = 0; pm < 2; pm++) {
          oaccT[mt8][pm][0] *= alpha[pm]; oaccT[mt8][pm][1] *= alpha[pm];
          oaccT[mt8][pm][2] *= alpha[pm]; oaccT[mt8][pm][3] *= alpha[pm];
        }

      // ---- O^T += V^T P^T (A=V^T frag from Vs; B=P^T frag = own Ps rows, b128) ----
#pragma unroll
      for (int ks = 0; ks < 2; ks++) {
        short8 pf[2];
#pragma unroll
        for (int pm = 0; pm < 2; pm++)
          pf[pm] = *(const short8*)&Ps[(w * 32 + pm * 16 + lc) * 72 + ks * 32 + quad * 8];
#pragma unroll
        for (int mt8 = 0; mt8 < 8; mt8++) {
          int n = mt8 * 16 + lc;
          short8 vf = *(const short8*)&Vs[n * 64 + (((ks * 4 + quad) ^ (n & 7)) * 8)];
#pragma unroll
          for (int pm = 0; pm < 2; pm++)
            oaccT[mt8][pm] = __builtin_amdgcn_mfma_f32_16x16x32_bf16(vf, pf[pm], oaccT[mt8][pm], 0, 0, 0);
        }
      }
    }
  }

  // final l reduce (2 shuffles), then O^T -> O write: 4 consecutive hd per lane = b64 store
#pragma unroll
  for (int pm = 0; pm < 2; pm++) {
    l_run[pm] += __shfl_xor(l_run[pm], 16);
    l_run[pm] += __shfl_xor(l_run[pm], 32);
    float inv = 1.f / l_run[pm];
    size_t obase = ((size_t)(b * S_LEN + wrow + pm * 16 + lc)) * DMODEL + h * HDIM;
#pragma unroll
    for (int mt8 = 0; mt8 < 8; mt8++) {
      ushort4 o;
      o.x = f2b(oaccT[mt8][pm][0] * inv);
      o.y = f2b(oaccT[mt8][pm][1] * inv);
      o.z = f2b(oaccT[mt8][pm][2] * inv);
      o.w = f2b(oaccT[mt8][pm][3] * inv);
      *(ushort4*)&Og[obase + mt8 * 16 + quad * 4] = o;
    }
  }
}

// ---------------- launch ----------------
extern "C" void kernel_launch(void* const* d_in, const int* in_sizes, int n_in,
                              void* d_out, int out_size, void* d_ws, size_t ws_size,
                              hipStream_t stream) {
  const float* x  = (const float*)d_in[0];
  const float* Wq = (const float*)d_in[1];
  const float* bq = (const float*)d_in[2];
  const float* Wk = (const float*)d_in[3];
  const float* bk = (const float*)d_in[4];
  const float* Wv = (const float*)d_in[5];
  const float* bv = (const float*)d_in[6];
  const float* Wo = (const float*)d_in[7];
  const float* bo = (const float*)d_in[8];

  const int M = 2 * S_LEN;  // 4096
  const int N = DMODEL, K = DMODEL;

  char* w = (char*)d_ws;  // needs 112 MB
  unsigned short* xb  = (unsigned short*)(w);
  unsigned short* Wqb = (unsigned short*)(w + (size_t)16 * (1 << 20));
  unsigned short* Wkb = (unsigned short*)(w + (size_t)24 * (1 << 20));
  unsigned short* Wvb = (unsigned short*)(w + (size_t)32 * (1 << 20));
  unsigned short* Wob = (unsigned short*)(w + (size_t)40 * (1 << 20));
  unsigned short* Qb  = (unsigned short*)(w + (size_t)48 * (1 << 20));
  unsigned short* Kb  = (unsigned short*)(w + (size_t)64 * (1 << 20));
  unsigned short* Vtb = (unsigned short*)(w + (size_t)80 * (1 << 20));
  unsigned short* Ob  = (unsigned short*)(w + (size_t)96 * (1 << 20));

  cvt_all<<<dim3(4096, 6), 256, 0, stream>>>(x, Wq, Wk, Wv, Wo, xb, Wqb, Wkb, Wvb, Wob);

  dim3 gg(N / 128, M / 128);
  // Q scale: log2(e)/sqrt(128) so attention softmax can use exp2 directly
  const float qscale = 0.08838834764831843f * 1.4426950408889634f;
  gemm_bt<0><<<gg, 256, 0, stream>>>(xb, Wqb, bq, Qb, M, N, K, qscale);
  gemm_bt<0><<<gg, 256, 0, stream>>>(xb, Wkb, bk, Kb, M, N, K, 1.f);
  gemm_bt<1><<<gg, 256, 0, stream>>>(xb, Wvb, bv, Vtb, M, N, K, 1.f);

  attn_fwd<<<dim3(16, 32), 256, 0, stream>>>(Qb, Kb, Vtb, Ob);

  gemm_bt<2><<<gg, 256, 0, stream>>>(Ob, Wob, bo, d_out, M, N, K, 1.f);
}